// Round 5
// baseline (1966.473 us; speedup 1.0000x reference)
//
#include <hip/hip_runtime.h>
#include <math.h>

#define DEV __device__ __forceinline__

DEV float lrelu_f(float v) { return v > 0.f ? v : 0.1f * v; }

DEV unsigned short f2bf(float f) {
    unsigned u = __builtin_bit_cast(unsigned, f);
    unsigned r = u + 0x7FFFu + ((u >> 16) & 1u);
    return (unsigned short)(r >> 16);
}

DEV float bf2f(unsigned short s) {
    return __builtin_bit_cast(float, (unsigned)s << 16);
}

typedef __attribute__((ext_vector_type(8))) short bh8;
typedef __attribute__((ext_vector_type(16))) float f16acc;

#define MFMA32(acc, a, b) acc = __builtin_amdgcn_mfma_f32_32x32x16_bf16(a, b, acc, 0, 0, 0)

// ---------------------------------------------------------------------------
// Weight transpose: src [L][O][KK] -> dst [L][KK][O]  (head only)
// ---------------------------------------------------------------------------
__global__ void transpose_w(const float* __restrict__ src, float* __restrict__ dst,
                            int L, int O, int KK) {
    int idx = blockIdx.x * 256 + threadIdx.x;
    int tot = L * O * KK;
    if (idx >= tot) return;
    int l = idx / (O * KK);
    int r = idx - l * (O * KK);
    int o = r / KK;
    int k = r - o * KK;
    dst[((size_t)l * KK + k) * O + o] = src[idx];
}

// ---------------------------------------------------------------------------
// Pack 3x3 conv weights [L][64 o][64 cin][3][3] -> frag layout
// [L][36 chunk][2 nt][64 lane][8 j] bf16, k = tap*64+cin, o = nt*32+(lane&31)
// ---------------------------------------------------------------------------
__global__ void pack3x3(const float* __restrict__ src, unsigned short* __restrict__ dst, int L) {
    int idx = blockIdx.x * 256 + threadIdx.x;
    if (idx >= L * 4608) return;
    int l = idx / 4608;
    int r = idx - l * 4608;
    int c = r >> 7;
    int rr = r & 127;
    int nt = rr >> 6, lane = rr & 63;
    int o = nt * 32 + (lane & 31);
    int kg = lane >> 5;
    unsigned short v[8];
#pragma unroll
    for (int j = 0; j < 8; ++j) {
        int k = c * 16 + kg * 8 + j;
        int t = k >> 6, cin = k & 63;
        v[j] = f2bf(src[(((size_t)l * 64 + o) * 64 + cin) * 9 + t]);
    }
    uint4 u;
    u.x = v[0] | ((unsigned)v[1] << 16);
    u.y = v[2] | ((unsigned)v[3] << 16);
    u.z = v[4] | ((unsigned)v[5] << 16);
    u.w = v[6] | ((unsigned)v[7] << 16);
    *(uint4*)(dst + (size_t)idx * 8) = u;
}

// ---------------------------------------------------------------------------
// Pack da 1x1 weights [L][64 o][64 cin] -> [L][4 chunk][2 nt][64][8] bf16
// ---------------------------------------------------------------------------
__global__ void pack_da(const float* __restrict__ src, unsigned short* __restrict__ dst, int L) {
    int idx = blockIdx.x * 256 + threadIdx.x;
    if (idx >= L * 512) return;
    int l = idx >> 9;
    int r = idx & 511;
    int c = r >> 7;
    int rr = r & 127;
    int nt = rr >> 6, lane = rr & 63;
    int o = nt * 32 + (lane & 31);
    int kg = lane >> 5;
    unsigned short v[8];
#pragma unroll
    for (int j = 0; j < 8; ++j) {
        int cin = c * 16 + kg * 8 + j;
        v[j] = f2bf(src[((size_t)l * 64 + o) * 64 + cin]);
    }
    uint4 u;
    u.x = v[0] | ((unsigned)v[1] << 16);
    u.y = v[2] | ((unsigned)v[3] << 16);
    u.z = v[4] | ((unsigned)v[5] << 16);
    u.w = v[6] | ((unsigned)v[7] << 16);
    *(uint4*)(dst + (size_t)idx * 8) = u;
}

// ---------------------------------------------------------------------------
// Pack up conv weights [256 o][64 cin][3][3] -> [36 chunk][8 nt][64][8] bf16
// ---------------------------------------------------------------------------
__global__ void pack_up(const float* __restrict__ src, unsigned short* __restrict__ dst) {
    int idx = blockIdx.x * 256 + threadIdx.x;
    if (idx >= 18432) return;
    int c = idx >> 9;
    int nt = (idx >> 6) & 7;
    int lane = idx & 63;
    int o = nt * 32 + (lane & 31);
    int kg = lane >> 5;
    unsigned short v[8];
#pragma unroll
    for (int j = 0; j < 8; ++j) {
        int k = c * 16 + kg * 8 + j;
        int t = k >> 6, cin = k & 63;
        v[j] = f2bf(src[((size_t)o * 64 + cin) * 9 + t]);
    }
    uint4 u;
    u.x = v[0] | ((unsigned)v[1] << 16);
    u.y = v[2] | ((unsigned)v[3] << 16);
    u.z = v[4] | ((unsigned)v[5] << 16);
    u.w = v[6] | ((unsigned)v[7] << 16);
    *(uint4*)(dst + (size_t)idx * 8) = u;
}

// ---------------------------------------------------------------------------
// Pack tail conv weights [3 o][64 cin][3][3] -> [36 chunk][64 lane][8] bf16
// N padded 3 -> 32 with zeros.
// ---------------------------------------------------------------------------
__global__ void pack_tail(const float* __restrict__ src, unsigned short* __restrict__ dst) {
    int idx = blockIdx.x * 256 + threadIdx.x;
    if (idx >= 2304) return;
    int c = idx >> 6;
    int lane = idx & 63;
    int o = lane & 31;
    int kg = lane >> 5;
    unsigned short v[8];
#pragma unroll
    for (int j = 0; j < 8; ++j) {
        int k = c * 16 + kg * 8 + j;
        int t = k >> 6, cin = k & 63;
        v[j] = (o < 3) ? f2bf(src[((size_t)o * 64 + cin) * 9 + t]) : (unsigned short)0;
    }
    uint4 u;
    u.x = v[0] | ((unsigned)v[1] << 16);
    u.y = v[2] | ((unsigned)v[3] << 16);
    u.z = v[4] | ((unsigned)v[5] << 16);
    u.w = v[6] | ((unsigned)v[7] << 16);
    *(uint4*)(dst + (size_t)idx * 8) = u;
}

// ---------------------------------------------------------------------------
// kv = lrelu(k_v @ comp_w.T)
// ---------------------------------------------------------------------------
__global__ void kv_kernel(const float* __restrict__ kvin, const float* __restrict__ comp_w,
                          float* __restrict__ kv) {
    int b = blockIdx.x, c = threadIdx.x;
    const float* a = kvin + b * 256;
    const float* w = comp_w + c * 256;
    float s = 0.f;
    for (int m = 0; m < 256; ++m) s += a[m] * w[m];
    kv[b * 64 + c] = lrelu_f(s);
}

// ---------------------------------------------------------------------------
// Per-(layer,batch) dynamic kernel + CA attention precompute.
// ---------------------------------------------------------------------------
__global__ void kerprep(const float* __restrict__ kv, const float* __restrict__ kw1,
                        const float* __restrict__ kw2, const float* __restrict__ caw1,
                        const float* __restrict__ caw2, float* __restrict__ ker_all,
                        float* __restrict__ att_all) {
    int l = blockIdx.x >> 4;
    int b = blockIdx.x & 15;
    int c = threadIdx.x;
    __shared__ float kvb[64];
    __shared__ float t1[64];
    __shared__ float a1[8];
    kvb[c] = kv[b * 64 + c];
    __syncthreads();
    {
        const float* w1 = kw1 + (size_t)l * 4096 + c * 64;
        float s = 0.f;
        for (int j = 0; j < 64; ++j) s += kvb[j] * w1[j];
        t1[c] = lrelu_f(s);
    }
    if (c < 8) {
        const float* cw1 = caw1 + (size_t)l * 512 + c * 64;
        float s = 0.f;
        for (int j = 0; j < 64; ++j) s += kvb[j] * cw1[j];
        a1[c] = lrelu_f(s);
    }
    __syncthreads();
    const float* w2 = kw2 + (size_t)l * 576 * 64;
    for (int t = 0; t < 9; ++t) {
        const float* row = w2 + (size_t)(c * 9 + t) * 64;
        float s = 0.f;
        for (int j = 0; j < 64; ++j) s += t1[j] * row[j];
        ker_all[(((size_t)l * 16 + b) * 9 + t) * 64 + c] = s;
    }
    {
        const float* c2 = caw2 + (size_t)l * 512 + c * 8;
        float s = 0.f;
        for (int r = 0; r < 8; ++r) s += a1[r] * c2[r];
        att_all[((size_t)l * 16 + b) * 64 + c] = 1.f / (1.f + expf(-s));
    }
}

// ---------------------------------------------------------------------------
// Head conv: x NCHW [16,3,64,64] fp32 -> x0,res fp32 + shadow bf16 (NHWC)
// ---------------------------------------------------------------------------
__global__ __launch_bounds__(256) void head_conv(const float* __restrict__ x,
                                                 const float* __restrict__ wt,
                                                 const float* __restrict__ bias,
                                                 float* __restrict__ x0,
                                                 float* __restrict__ res,
                                                 unsigned short* __restrict__ resS) {
    int t = threadIdx.x;
    int co = t & 63, q = t >> 6;
    int bid = blockIdx.x;
    int b = bid >> 7;
    int rem = bid & 127;
    int y = rem >> 1;
    int xs = (rem & 1) * 32 + q * 8;

    float bv = bias[co];
    float acc[8];
#pragma unroll
    for (int p = 0; p < 8; ++p) acc[p] = bv;

    int coff[10];
    bool cok[10];
#pragma unroll
    for (int i = 0; i < 10; ++i) {
        int col = xs - 1 + i;
        cok[i] = (col >= 0) && (col < 64);
        coff[i] = cok[i] ? col : 0;
    }
    for (int cin = 0; cin < 3; ++cin) {
#pragma unroll
        for (int ky = 0; ky < 3; ++ky) {
            int row = y + ky - 1;
            bool rok = (row >= 0) && (row < 64);
            const float* rp = x + ((size_t)(b * 3 + cin) * 64 + (rok ? row : 0)) * 64;
            float v[10];
#pragma unroll
            for (int i = 0; i < 10; ++i) v[i] = (rok && cok[i]) ? rp[coff[i]] : 0.f;
            const float* wp = wt + ((cin * 3 + ky) * 3) * 64 + co;
            float w0 = wp[0], w1 = wp[64], w2 = wp[128];
#pragma unroll
            for (int p = 0; p < 8; ++p) acc[p] += w0 * v[p] + w1 * v[p + 1] + w2 * v[p + 2];
        }
    }
    size_t ob = (((size_t)b * 64 + y) * 64 + xs) * 64 + co;
#pragma unroll
    for (int p = 0; p < 8; ++p) {
        x0[ob + (size_t)p * 64] = acc[p];
        res[ob + (size_t)p * 64] = acc[p];
        resS[ob + (size_t)p * 64] = f2bf(acc[p]);
    }
}

// ---------------------------------------------------------------------------
// MFMA 3x3 conv 64->64, bf16 NHWC in, optional fp32 resid, fp32/bf16 outs.
// Tile 16x16 (256 px), halo 18x18=324, LDS stride 72 shorts. Block 256 = 4
// waves; wave w: M-tiles {2w,2w+1} (px w*64..w*64+63) x 2 N-tiles. Grid 256.
// ---------------------------------------------------------------------------
__global__ __launch_bounds__(256) void conv3x3_mfma(const unsigned short* __restrict__ in,
                                                    const unsigned short* __restrict__ wp,
                                                    const float* __restrict__ bias,
                                                    const float* __restrict__ residF,
                                                    float* __restrict__ outF,
                                                    unsigned short* __restrict__ outB,
                                                    int act) {
    __shared__ unsigned short sm[324 * 72];
    int tid = threadIdx.x;
    int bid = blockIdx.x;
    int b = bid >> 4, ty = (bid >> 2) & 3, tx = bid & 3;
    const unsigned short* inb = in + (size_t)b * 262144;

    for (int i = tid; i < 2592; i += 256) {
        int px = i >> 3, c8 = i & 7;
        int hy = px / 18, hx = px - hy * 18;
        int row = ty * 16 + hy - 1, col = tx * 16 + hx - 1;
        uint4 u = make_uint4(0u, 0u, 0u, 0u);
        if (row >= 0 && row < 64 && col >= 0 && col < 64)
            u = *(const uint4*)(inb + (((size_t)row * 64 + col) * 64 + c8 * 8));
        *(uint4*)&sm[px * 72 + c8 * 8] = u;
    }
    __syncthreads();

    int lane = tid & 63, w = tid >> 6;
    int l31 = lane & 31, kg8 = (lane >> 5) * 8;
    int mbase = w * 64;
    int p0 = mbase + l31;
    int ly0 = p0 >> 4, lx0 = p0 & 15;

    f16acc a00 = {0,0,0,0,0,0,0,0,0,0,0,0,0,0,0,0};
    f16acc a01 = a00, a10 = a00, a11 = a00;

#pragma unroll
    for (int t = 0; t < 9; ++t) {
        int tyt = t / 3, txt = t - tyt * 3;
        int base0 = ((ly0 + tyt) * 18 + lx0 + txt) * 72 + kg8;
        int base1 = base0 + 2592;  // +32 px = +2 halo rows
#pragma unroll
        for (int cc = 0; cc < 4; ++cc) {
            int c = t * 4 + cc;
            bh8 A0 = *(const bh8*)&sm[base0 + cc * 16];
            bh8 A1 = *(const bh8*)&sm[base1 + cc * 16];
            bh8 B0 = *(const bh8*)&wp[((size_t)(c * 2 + 0) * 64 + lane) * 8];
            bh8 B1 = *(const bh8*)&wp[((size_t)(c * 2 + 1) * 64 + lane) * 8];
            MFMA32(a00, A0, B0);
            MFMA32(a01, A0, B1);
            MFMA32(a10, A1, B0);
            MFMA32(a11, A1, B1);
        }
    }

    float bias0 = bias[l31], bias1 = bias[32 + l31];
    int hi = lane >> 5;
    size_t outb = (size_t)b * 262144;
#pragma unroll
    for (int r = 0; r < 16; ++r) {
        int rowm = (r & 3) + 8 * (r >> 2) + 4 * hi;
        int m0 = mbase + rowm;
        int gy0 = ty * 16 + (m0 >> 4), gx0 = tx * 16 + (m0 & 15);
        size_t i0 = outb + (((size_t)gy0 * 64 + gx0) * 64);
        int m1 = m0 + 32;
        int gy1 = ty * 16 + (m1 >> 4), gx1 = tx * 16 + (m1 & 15);
        size_t i1 = outb + (((size_t)gy1 * 64 + gx1) * 64);
        float v00 = a00[r] + bias0, v01 = a01[r] + bias1;
        float v10 = a10[r] + bias0, v11 = a11[r] + bias1;
        if (residF) {
            v00 += residF[i0 + l31];
            v01 += residF[i0 + 32 + l31];
            v10 += residF[i1 + l31];
            v11 += residF[i1 + 32 + l31];
        }
        if (act) {
            v00 = lrelu_f(v00); v01 = lrelu_f(v01);
            v10 = lrelu_f(v10); v11 = lrelu_f(v11);
        }
        if (outF) {
            outF[i0 + l31] = v00;
            outF[i0 + 32 + l31] = v01;
            outF[i1 + l31] = v10;
            outF[i1 + 32 + l31] = v11;
        }
        if (outB) {
            outB[i0 + l31] = f2bf(v00);
            outB[i0 + 32 + l31] = f2bf(v01);
            outB[i1 + l31] = f2bf(v10);
            outB[i1 + 32 + l31] = f2bf(v11);
        }
    }
}

// ---------------------------------------------------------------------------
// Fused DA_conv (MFMA): bf16 in -> LDS halo -> depthwise 3x3 (fp32 math) ->
// mid LDS bf16 -> 1x1 MFMA (B in LDS) -> +cb + in*att -> lrelu -> bf16 out.
// Tile 16x8, halo 18x10=180. Block 256 = 4 waves (wave: 1M x 2N). Grid 512.
// LDS 52.5 KB -> 2 blocks/CU.
// ---------------------------------------------------------------------------
__global__ __launch_bounds__(256) void da_mfma(const unsigned short* __restrict__ in,
                                               const unsigned short* __restrict__ wp,
                                               const float* __restrict__ cb,
                                               const float* __restrict__ kerT,
                                               const float* __restrict__ attv,
                                               unsigned short* __restrict__ out) {
    __shared__ unsigned short sm[180 * 72];
    __shared__ unsigned short mid[128 * 72];
    __shared__ unsigned short bds[4096];
    int tid = threadIdx.x;
    int bid = blockIdx.x;
    int b = bid >> 5;
    int rem = bid & 31;
    int ty = rem >> 2, tx = rem & 3;
    const unsigned short* inb = in + (size_t)b * 262144;

    for (int i = tid; i < 1440; i += 256) {
        int px = i >> 3, c8 = i & 7;
        int hy = px / 18, hx = px - hy * 18;
        int row = ty * 8 + hy - 1, col = tx * 16 + hx - 1;
        uint4 u = make_uint4(0u, 0u, 0u, 0u);
        if (row >= 0 && row < 64 && col >= 0 && col < 64)
            u = *(const uint4*)(inb + (((size_t)row * 64 + col) * 64 + c8 * 8));
        *(uint4*)&sm[px * 72 + c8 * 8] = u;
    }
#pragma unroll
    for (int i = 0; i < 2; ++i) {
        int idx = i * 256 + tid;
        *(uint4*)&bds[idx * 8] = *(const uint4*)&wp[idx * 8];
    }
    __syncthreads();

    // depthwise from LDS: thread (c, q); q handles rows 2q, 2q+1
    {
        int c = tid & 63, q = tid >> 6;
        const float* kb = kerT + (size_t)b * 576;
        float k[9];
#pragma unroll
        for (int t = 0; t < 9; ++t) k[t] = kb[t * 64 + c];
#pragma unroll
        for (int rr = 0; rr < 2; ++rr) {
            int ly = q * 2 + rr;
            float m[16];
#pragma unroll
            for (int xx = 0; xx < 16; ++xx) m[xx] = 0.f;
#pragma unroll
            for (int ky = 0; ky < 3; ++ky) {
                int hr = ly + ky;
                float v[18];
#pragma unroll
                for (int i = 0; i < 18; ++i) v[i] = bf2f(sm[(hr * 18 + i) * 72 + c]);
                float k0 = k[ky * 3], k1 = k[ky * 3 + 1], k2 = k[ky * 3 + 2];
#pragma unroll
                for (int xx = 0; xx < 16; ++xx) m[xx] += k0 * v[xx] + k1 * v[xx + 1] + k2 * v[xx + 2];
            }
#pragma unroll
            for (int xx = 0; xx < 16; ++xx)
                mid[(ly * 16 + xx) * 72 + c] = f2bf(lrelu_f(m[xx]));
        }
    }
    __syncthreads();

    // 1x1 MFMA, K=64
    int lane = tid & 63, w = tid >> 6;
    int l31 = lane & 31, kg8 = (lane >> 5) * 8;
    int base = (w * 32 + l31) * 72 + kg8;

    f16acc a0 = {0,0,0,0,0,0,0,0,0,0,0,0,0,0,0,0};
    f16acc a1 = a0;
#pragma unroll
    for (int cc = 0; cc < 4; ++cc) {
        bh8 A = *(const bh8*)&mid[base + cc * 16];
        bh8 B0 = *(const bh8*)&bds[((cc * 2 + 0) * 64 + lane) * 8];
        bh8 B1 = *(const bh8*)&bds[((cc * 2 + 1) * 64 + lane) * 8];
        MFMA32(a0, A, B0);
        MFMA32(a1, A, B1);
    }

    float cb0 = cb[l31], cb1 = cb[32 + l31];
    float at0 = attv[b * 64 + l31], at1 = attv[b * 64 + 32 + l31];
    int hi = lane >> 5;
    size_t outb = (size_t)b * 262144;
#pragma unroll
    for (int r = 0; r < 16; ++r) {
        int rowm = (r & 3) + 8 * (r >> 2) + 4 * hi;
        int m = w * 32 + rowm;
        int gy = ty * 8 + (m >> 4), gx = tx * 16 + (m & 15);
        size_t i0 = outb + (((size_t)gy * 64 + gx) * 64);
        float v0 = a0[r] + cb0 + bf2f(in[i0 + l31]) * at0;
        float v1 = a1[r] + cb1 + bf2f(in[i0 + 32 + l31]) * at1;
        out[i0 + l31] = f2bf(lrelu_f(v0));
        out[i0 + 32 + l31] = f2bf(lrelu_f(v1));
    }
}

// ---------------------------------------------------------------------------
// Up conv 64->256 (MFMA) + fused pixel shuffle. bf16 in/out.
// Tile 8x8 px, halo 10x10. Wave w: co [w*64, w*64+64). Grid 1024.
// ---------------------------------------------------------------------------
__global__ __launch_bounds__(256) void up_mfma(const unsigned short* __restrict__ in,
                                               const unsigned short* __restrict__ wp,
                                               const float* __restrict__ bias,
                                               unsigned short* __restrict__ shuf) {
    __shared__ unsigned short sm[100 * 72];
    int tid = threadIdx.x;
    int bid = blockIdx.x;
    int b = bid >> 6;
    int t6 = bid & 63;
    int ty = t6 >> 3, tx = t6 & 7;
    const unsigned short* inb = in + (size_t)b * 262144;

    for (int i = tid; i < 800; i += 256) {
        int px = i >> 3, c8 = i & 7;
        int hy = px / 10, hx = px - hy * 10;
        int row = ty * 8 + hy - 1, col = tx * 8 + hx - 1;
        uint4 u = make_uint4(0u, 0u, 0u, 0u);
        if (row >= 0 && row < 64 && col >= 0 && col < 64)
            u = *(const uint4*)(inb + (((size_t)row * 64 + col) * 64 + c8 * 8));
        *(uint4*)&sm[px * 72 + c8 * 8] = u;
    }
    __syncthreads();

    int lane = tid & 63, w = tid >> 6;
    int l31 = lane & 31, kg8 = (lane >> 5) * 8;
    int ly0 = l31 >> 3, lx0 = l31 & 7;

    f16acc a00 = {0,0,0,0,0,0,0,0,0,0,0,0,0,0,0,0};
    f16acc a01 = a00, a10 = a00, a11 = a00;

#pragma unroll
    for (int t = 0; t < 9; ++t) {
        int tyt = t / 3, txt = t - tyt * 3;
        int base0 = ((ly0 + tyt) * 10 + lx0 + txt) * 72 + kg8;
        int base1 = base0 + 2880;  // +32 px = +4 halo rows
#pragma unroll
        for (int cc = 0; cc < 4; ++cc) {
            int c = t * 4 + cc;
            bh8 A0 = *(const bh8*)&sm[base0 + cc * 16];
            bh8 A1 = *(const bh8*)&sm[base1 + cc * 16];
            bh8 B0 = *(const bh8*)&wp[((size_t)(c * 8 + w * 2 + 0) * 64 + lane) * 8];
            bh8 B1 = *(const bh8*)&wp[((size_t)(c * 8 + w * 2 + 1) * 64 + lane) * 8];
            MFMA32(a00, A0, B0);
            MFMA32(a01, A0, B1);
            MFMA32(a10, A1, B0);
            MFMA32(a11, A1, B1);
        }
    }

    int co0 = w * 64 + l31, co1 = co0 + 32;
    float bias0 = bias[co0], bias1 = bias[co1];
    int ch0 = co0 >> 2, r10 = (co0 >> 1) & 1, r20 = co0 & 1;
    int ch1 = co1 >> 2, r11 = (co1 >> 1) & 1, r21 = co1 & 1;
    int hi = lane >> 5;
#pragma unroll
    for (int r = 0; r < 16; ++r) {
        int rowm = (r & 3) + 8 * (r >> 2) + 4 * hi;
#pragma unroll
        for (int mt = 0; mt < 2; ++mt) {
            int m = mt * 32 + rowm;
            int y = ty * 8 + (m >> 3), x = tx * 8 + (m & 7);
            float va = (mt == 0) ? a00[r] : a10[r];
            float vb = (mt == 0) ? a01[r] : a11[r];
            shuf[(((size_t)b * 128 + 2 * y + r10) * 128 + 2 * x + r20) * 64 + ch0] = f2bf(va + bias0);
            shuf[(((size_t)b * 128 + 2 * y + r11) * 128 + 2 * x + r21) * 64 + ch1] = f2bf(vb + bias1);
        }
    }
}

// ---------------------------------------------------------------------------
// Tail conv 64->3 as MFMA, N padded to 32. shuf bf16 NHWC -> out NCHW fp32.
// Tile 16x16, halo 18x18. Grid 1024.
// ---------------------------------------------------------------------------
__global__ __launch_bounds__(256) void tail_mfma(const unsigned short* __restrict__ shuf,
                                                 const unsigned short* __restrict__ wp,
                                                 const float* __restrict__ bias,
                                                 float* __restrict__ outp) {
    __shared__ unsigned short sm[324 * 72];
    int tid = threadIdx.x;
    int bid = blockIdx.x;
    int b = bid >> 6;
    int rem = bid & 63;
    int ty = rem >> 3, tx = rem & 7;
    const unsigned short* sb = shuf + (size_t)b * 128 * 128 * 64;

    for (int i = tid; i < 2592; i += 256) {
        int px = i >> 3, c8 = i & 7;
        int hy = px / 18, hx = px - hy * 18;
        int row = ty * 16 + hy - 1, col = tx * 16 + hx - 1;
        uint4 u = make_uint4(0u, 0u, 0u, 0u);
        if (row >= 0 && row < 128 && col >= 0 && col < 128)
            u = *(const uint4*)(sb + (((size_t)row * 128 + col) * 64 + c8 * 8));
        *(uint4*)&sm[px * 72 + c8 * 8] = u;
    }
    __syncthreads();

    int lane = tid & 63, w = tid >> 6;
    int l31 = lane & 31, kg8 = (lane >> 5) * 8;
    int mbase = w * 64;
    int p0 = mbase + l31;
    int ly0 = p0 >> 4, lx0 = p0 & 15;

    f16acc a0 = {0,0,0,0,0,0,0,0,0,0,0,0,0,0,0,0};
    f16acc a1 = a0;

#pragma unroll
    for (int t = 0; t < 9; ++t) {
        int tyt = t / 3, txt = t - tyt * 3;
        int base0 = ((ly0 + tyt) * 18 + lx0 + txt) * 72 + kg8;
        int base1 = base0 + 2592;
#pragma unroll
        for (int cc = 0; cc < 4; ++cc) {
            int c = t * 4 + cc;
            bh8 A0 = *(const bh8*)&sm[base0 + cc * 16];
            bh8 A1 = *(const bh8*)&sm[base1 + cc * 16];
            bh8 B = *(const bh8*)&wp[((size_t)c * 64 + lane) * 8];
            MFMA32(a0, A0, B);
            MFMA32(a1, A1, B);
        }
    }

    if (l31 < 3) {
        float bv = bias[l31];
        int hi = lane >> 5;
        size_t ob = ((size_t)b * 3 + l31) * 16384;
#pragma unroll
        for (int r = 0; r < 16; ++r) {
            int rowm = (r & 3) + 8 * (r >> 2) + 4 * hi;
            int m0 = mbase + rowm;
            int gy0 = ty * 16 + (m0 >> 4), gx0 = tx * 16 + (m0 & 15);
            outp[ob + (size_t)gy0 * 128 + gx0] = a0[r] + bv;
            int m1 = m0 + 32;
            int gy1 = ty * 16 + (m1 >> 4), gx1 = tx * 16 + (m1 & 15);
            outp[ob + (size_t)gy1 * 128 + gx1] = a1[r] + bv;
        }
    }
}

// ---------------------------------------------------------------------------
extern "C" void kernel_launch(void* const* d_in, const int* in_sizes, int n_in,
                              void* d_out, int out_size, void* d_ws, size_t ws_size,
                              hipStream_t stream) {
    const float* x      = (const float*)d_in[0];
    const float* k_v    = (const float*)d_in[1];
    const float* head_w = (const float*)d_in[2];
    const float* head_b = (const float*)d_in[3];
    const float* comp_w = (const float*)d_in[4];
    const float* da_kw1 = (const float*)d_in[5];
    const float* da_kw2 = (const float*)d_in[6];
    const float* da_cw  = (const float*)d_in[7];
    const float* da_cb  = (const float*)d_in[8];
    const float* ca_w1  = (const float*)d_in[9];
    const float* ca_w2  = (const float*)d_in[10];
    const float* dab_cw = (const float*)d_in[11];
    const float* dab_cb = (const float*)d_in[12];
    const float* grp_w  = (const float*)d_in[13];
    const float* grp_b  = (const float*)d_in[14];
    const float* body_w = (const float*)d_in[15];
    const float* body_b = (const float*)d_in[16];
    const float* up_w   = (const float*)d_in[17];
    const float* up_b   = (const float*)d_in[18];
    const float* tail_w = (const float*)d_in[19];
    const float* tail_b = (const float*)d_in[20];

    char* base = (char*)d_ws;
    auto alloc = [&](size_t bytes) -> char* {
        char* p = base;
        base += (bytes + 255) & ~(size_t)255;
        return p;
    };
    unsigned short* wp_dab  = (unsigned short*)alloc((size_t)50 * 36864 * 2);
    unsigned short* wp_grp  = (unsigned short*)alloc((size_t)5 * 36864 * 2);
    unsigned short* wp_body = (unsigned short*)alloc((size_t)36864 * 2);
    unsigned short* wp_up   = (unsigned short*)alloc((size_t)147456 * 2);
    unsigned short* wp_da   = (unsigned short*)alloc((size_t)50 * 4096 * 2);
    unsigned short* wp_tail = (unsigned short*)alloc((size_t)18432 * 2);
    float* wT_head = (float*)alloc(1728 * 4);
    float* kvbuf   = (float*)alloc(1024 * 4);
    float* ker_all = (float*)alloc((size_t)460800 * 4);
    float* att_all = (float*)alloc((size_t)51200 * 4);
    const size_t ACT = (size_t)16 * 64 * 64 * 64;
    float* x0 = (float*)alloc(ACT * 4);
    float* rA = (float*)alloc(ACT * 4);
    float* rB = (float*)alloc(ACT * 4);
    float* rC = (float*)alloc(ACT * 4);
    unsigned short* sA = (unsigned short*)alloc(ACT * 2);
    unsigned short* sB = (unsigned short*)alloc(ACT * 2);
    unsigned short* sC = (unsigned short*)alloc(ACT * 2);
    unsigned short* t0 = (unsigned short*)alloc(ACT * 2);
    unsigned short* t1 = (unsigned short*)alloc(ACT * 2);
    unsigned short* shuf = (unsigned short*)alloc((size_t)16 * 128 * 128 * 64 * 2);

    pack3x3<<<900, 256, 0, stream>>>(dab_cw, wp_dab, 50);
    pack3x3<<<90, 256, 0, stream>>>(grp_w, wp_grp, 5);
    pack3x3<<<18, 256, 0, stream>>>(body_w, wp_body, 1);
    pack_da<<<100, 256, 0, stream>>>(da_cw, wp_da, 50);
    pack_up<<<72, 256, 0, stream>>>(up_w, wp_up);
    pack_tail<<<9, 256, 0, stream>>>(tail_w, wp_tail);
    transpose_w<<<7, 256, 0, stream>>>(head_w, wT_head, 1, 64, 27);

    kv_kernel<<<16, 64, 0, stream>>>(k_v, comp_w, kvbuf);
    kerprep<<<800, 64, 0, stream>>>(kvbuf, da_kw1, da_kw2, ca_w1, ca_w2, ker_all, att_all);

    head_conv<<<2048, 256, 0, stream>>>(x, wT_head, head_b, x0, rA, sA);

    for (int g = 0; g < 5; ++g) {
        float* curF = rA;
        unsigned short* curS = sA;
        for (int n = 0; n < 5; ++n) {
            int l0 = (g * 5 + n) * 2, l1 = l0 + 1;
            da_mfma<<<512, 256, 0, stream>>>(curS, wp_da + (size_t)l0 * 4096,
                                             da_cb + (size_t)l0 * 64, ker_all + (size_t)l0 * 9216,
                                             att_all + (size_t)l0 * 1024, t0);
            conv3x3_mfma<<<256, 256, 0, stream>>>(t0, wp_dab + (size_t)l0 * 36864,
                                                  dab_cb + (size_t)l0 * 64, nullptr,
                                                  nullptr, t1, 1);
            da_mfma<<<512, 256, 0, stream>>>(t1, wp_da + (size_t)l1 * 4096,
                                             da_cb + (size_t)l1 * 64, ker_all + (size_t)l1 * 9216,
                                             att_all + (size_t)l1 * 1024, t0);
            float* outF = (curF == rB) ? rC : rB;
            unsigned short* outS = (curS == sB) ? sC : sB;
            conv3x3_mfma<<<256, 256, 0, stream>>>(t0, wp_dab + (size_t)l1 * 36864,
                                                  dab_cb + (size_t)l1 * 64, curF,
                                                  outF, outS, 0);
            curF = outF;
            curS = outS;
        }
        // after 5 DABs cur == rB/sB; spare is rC/sC
        conv3x3_mfma<<<256, 256, 0, stream>>>(curS, wp_grp + (size_t)g * 36864,
                                              grp_b + (size_t)g * 64, rA, rC, sC, 0);
        // rotate: new group input = rC
        float* tf = rA; rA = rC; rC = tf;
        unsigned short* ts = sA; sA = sC; sC = ts;
    }
    conv3x3_mfma<<<256, 256, 0, stream>>>(sA, wp_body, body_b, x0, nullptr, t0, 0);

    up_mfma<<<1024, 256, 0, stream>>>(t0, wp_up, up_b, shuf);
    tail_mfma<<<1024, 256, 0, stream>>>(shuf, wp_tail, tail_b, (float*)d_out);
}

// Round 6
// 1533.931 us; speedup vs baseline: 1.2820x; 1.2820x over previous
//
#include <hip/hip_runtime.h>
#include <math.h>

#define DEV __device__ __forceinline__

DEV float lrelu_f(float v) { return v > 0.f ? v : 0.1f * v; }

DEV unsigned short f2bf(float f) {
    unsigned u = __builtin_bit_cast(unsigned, f);
    unsigned r = u + 0x7FFFu + ((u >> 16) & 1u);
    return (unsigned short)(r >> 16);
}

DEV float bf2f(unsigned short s) {
    return __builtin_bit_cast(float, (unsigned)s << 16);
}

typedef __attribute__((ext_vector_type(8))) short bh8;
typedef __attribute__((ext_vector_type(16))) float f16acc;

#define MFMA32(acc, a, b) acc = __builtin_amdgcn_mfma_f32_32x32x16_bf16(a, b, acc, 0, 0, 0)

// ---------------------------------------------------------------------------
// Weight transpose: src [L][O][KK] -> dst [L][KK][O]  (head only)
// ---------------------------------------------------------------------------
__global__ void transpose_w(const float* __restrict__ src, float* __restrict__ dst,
                            int L, int O, int KK) {
    int idx = blockIdx.x * 256 + threadIdx.x;
    int tot = L * O * KK;
    if (idx >= tot) return;
    int l = idx / (O * KK);
    int r = idx - l * (O * KK);
    int o = r / KK;
    int k = r - o * KK;
    dst[((size_t)l * KK + k) * O + o] = src[idx];
}

// ---------------------------------------------------------------------------
// Pack 3x3 conv weights [L][64 o][64 cin][3][3] -> frag layout
// [L][36 chunk][2 nt][64 lane][8 j] bf16, k = tap*64+cin, o = nt*32+(lane&31)
// ---------------------------------------------------------------------------
__global__ void pack3x3(const float* __restrict__ src, unsigned short* __restrict__ dst, int L) {
    int idx = blockIdx.x * 256 + threadIdx.x;
    if (idx >= L * 4608) return;
    int l = idx / 4608;
    int r = idx - l * 4608;
    int c = r >> 7;
    int rr = r & 127;
    int nt = rr >> 6, lane = rr & 63;
    int o = nt * 32 + (lane & 31);
    int kg = lane >> 5;
    unsigned short v[8];
#pragma unroll
    for (int j = 0; j < 8; ++j) {
        int k = c * 16 + kg * 8 + j;
        int t = k >> 6, cin = k & 63;
        v[j] = f2bf(src[(((size_t)l * 64 + o) * 64 + cin) * 9 + t]);
    }
    uint4 u;
    u.x = v[0] | ((unsigned)v[1] << 16);
    u.y = v[2] | ((unsigned)v[3] << 16);
    u.z = v[4] | ((unsigned)v[5] << 16);
    u.w = v[6] | ((unsigned)v[7] << 16);
    *(uint4*)(dst + (size_t)idx * 8) = u;
}

// ---------------------------------------------------------------------------
// Pack da 1x1 weights [L][64 o][64 cin] -> [L][4 chunk][2 nt][64][8] bf16
// ---------------------------------------------------------------------------
__global__ void pack_da(const float* __restrict__ src, unsigned short* __restrict__ dst, int L) {
    int idx = blockIdx.x * 256 + threadIdx.x;
    if (idx >= L * 512) return;
    int l = idx >> 9;
    int r = idx & 511;
    int c = r >> 7;
    int rr = r & 127;
    int nt = rr >> 6, lane = rr & 63;
    int o = nt * 32 + (lane & 31);
    int kg = lane >> 5;
    unsigned short v[8];
#pragma unroll
    for (int j = 0; j < 8; ++j) {
        int cin = c * 16 + kg * 8 + j;
        v[j] = f2bf(src[((size_t)l * 64 + o) * 64 + cin]);
    }
    uint4 u;
    u.x = v[0] | ((unsigned)v[1] << 16);
    u.y = v[2] | ((unsigned)v[3] << 16);
    u.z = v[4] | ((unsigned)v[5] << 16);
    u.w = v[6] | ((unsigned)v[7] << 16);
    *(uint4*)(dst + (size_t)idx * 8) = u;
}

// ---------------------------------------------------------------------------
// Pack up conv weights [256 o][64 cin][3][3] -> [36 chunk][8 nt][64][8] bf16
// ---------------------------------------------------------------------------
__global__ void pack_up(const float* __restrict__ src, unsigned short* __restrict__ dst) {
    int idx = blockIdx.x * 256 + threadIdx.x;
    if (idx >= 18432) return;
    int c = idx >> 9;
    int nt = (idx >> 6) & 7;
    int lane = idx & 63;
    int o = nt * 32 + (lane & 31);
    int kg = lane >> 5;
    unsigned short v[8];
#pragma unroll
    for (int j = 0; j < 8; ++j) {
        int k = c * 16 + kg * 8 + j;
        int t = k >> 6, cin = k & 63;
        v[j] = f2bf(src[((size_t)o * 64 + cin) * 9 + t]);
    }
    uint4 u;
    u.x = v[0] | ((unsigned)v[1] << 16);
    u.y = v[2] | ((unsigned)v[3] << 16);
    u.z = v[4] | ((unsigned)v[5] << 16);
    u.w = v[6] | ((unsigned)v[7] << 16);
    *(uint4*)(dst + (size_t)idx * 8) = u;
}

// ---------------------------------------------------------------------------
// Pack tail conv weights [3 o][64 cin][3][3] -> [36 chunk][64 lane][8] bf16
// N padded 3 -> 32 with zeros.
// ---------------------------------------------------------------------------
__global__ void pack_tail(const float* __restrict__ src, unsigned short* __restrict__ dst) {
    int idx = blockIdx.x * 256 + threadIdx.x;
    if (idx >= 2304) return;
    int c = idx >> 6;
    int lane = idx & 63;
    int o = lane & 31;
    int kg = lane >> 5;
    unsigned short v[8];
#pragma unroll
    for (int j = 0; j < 8; ++j) {
        int k = c * 16 + kg * 8 + j;
        int t = k >> 6, cin = k & 63;
        v[j] = (o < 3) ? f2bf(src[((size_t)o * 64 + cin) * 9 + t]) : (unsigned short)0;
    }
    uint4 u;
    u.x = v[0] | ((unsigned)v[1] << 16);
    u.y = v[2] | ((unsigned)v[3] << 16);
    u.z = v[4] | ((unsigned)v[5] << 16);
    u.w = v[6] | ((unsigned)v[7] << 16);
    *(uint4*)(dst + (size_t)idx * 8) = u;
}

// ---------------------------------------------------------------------------
// kv = lrelu(k_v @ comp_w.T)
// ---------------------------------------------------------------------------
__global__ void kv_kernel(const float* __restrict__ kvin, const float* __restrict__ comp_w,
                          float* __restrict__ kv) {
    int b = blockIdx.x, c = threadIdx.x;
    const float* a = kvin + b * 256;
    const float* w = comp_w + c * 256;
    float s = 0.f;
    for (int m = 0; m < 256; ++m) s += a[m] * w[m];
    kv[b * 64 + c] = lrelu_f(s);
}

// ---------------------------------------------------------------------------
// Per-(layer,batch) dynamic kernel + CA attention precompute.
// ---------------------------------------------------------------------------
__global__ void kerprep(const float* __restrict__ kv, const float* __restrict__ kw1,
                        const float* __restrict__ kw2, const float* __restrict__ caw1,
                        const float* __restrict__ caw2, float* __restrict__ ker_all,
                        float* __restrict__ att_all) {
    int l = blockIdx.x >> 4;
    int b = blockIdx.x & 15;
    int c = threadIdx.x;
    __shared__ float kvb[64];
    __shared__ float t1[64];
    __shared__ float a1[8];
    kvb[c] = kv[b * 64 + c];
    __syncthreads();
    {
        const float* w1 = kw1 + (size_t)l * 4096 + c * 64;
        float s = 0.f;
        for (int j = 0; j < 64; ++j) s += kvb[j] * w1[j];
        t1[c] = lrelu_f(s);
    }
    if (c < 8) {
        const float* cw1 = caw1 + (size_t)l * 512 + c * 64;
        float s = 0.f;
        for (int j = 0; j < 64; ++j) s += kvb[j] * cw1[j];
        a1[c] = lrelu_f(s);
    }
    __syncthreads();
    const float* w2 = kw2 + (size_t)l * 576 * 64;
    for (int t = 0; t < 9; ++t) {
        const float* row = w2 + (size_t)(c * 9 + t) * 64;
        float s = 0.f;
        for (int j = 0; j < 64; ++j) s += t1[j] * row[j];
        ker_all[(((size_t)l * 16 + b) * 9 + t) * 64 + c] = s;
    }
    {
        const float* c2 = caw2 + (size_t)l * 512 + c * 8;
        float s = 0.f;
        for (int r = 0; r < 8; ++r) s += a1[r] * c2[r];
        att_all[((size_t)l * 16 + b) * 64 + c] = 1.f / (1.f + expf(-s));
    }
}

// ---------------------------------------------------------------------------
// Head conv: x NCHW [16,3,64,64] fp32 -> x0,res fp32 + shadow bf16 (NHWC)
// ---------------------------------------------------------------------------
__global__ __launch_bounds__(256) void head_conv(const float* __restrict__ x,
                                                 const float* __restrict__ wt,
                                                 const float* __restrict__ bias,
                                                 float* __restrict__ x0,
                                                 float* __restrict__ res,
                                                 unsigned short* __restrict__ resS) {
    int t = threadIdx.x;
    int co = t & 63, q = t >> 6;
    int bid = blockIdx.x;
    int b = bid >> 7;
    int rem = bid & 127;
    int y = rem >> 1;
    int xs = (rem & 1) * 32 + q * 8;

    float bv = bias[co];
    float acc[8];
#pragma unroll
    for (int p = 0; p < 8; ++p) acc[p] = bv;

    int coff[10];
    bool cok[10];
#pragma unroll
    for (int i = 0; i < 10; ++i) {
        int col = xs - 1 + i;
        cok[i] = (col >= 0) && (col < 64);
        coff[i] = cok[i] ? col : 0;
    }
    for (int cin = 0; cin < 3; ++cin) {
#pragma unroll
        for (int ky = 0; ky < 3; ++ky) {
            int row = y + ky - 1;
            bool rok = (row >= 0) && (row < 64);
            const float* rp = x + ((size_t)(b * 3 + cin) * 64 + (rok ? row : 0)) * 64;
            float v[10];
#pragma unroll
            for (int i = 0; i < 10; ++i) v[i] = (rok && cok[i]) ? rp[coff[i]] : 0.f;
            const float* wp = wt + ((cin * 3 + ky) * 3) * 64 + co;
            float w0 = wp[0], w1 = wp[64], w2 = wp[128];
#pragma unroll
            for (int p = 0; p < 8; ++p) acc[p] += w0 * v[p] + w1 * v[p + 1] + w2 * v[p + 2];
        }
    }
    size_t ob = (((size_t)b * 64 + y) * 64 + xs) * 64 + co;
#pragma unroll
    for (int p = 0; p < 8; ++p) {
        x0[ob + (size_t)p * 64] = acc[p];
        res[ob + (size_t)p * 64] = acc[p];
        resS[ob + (size_t)p * 64] = f2bf(acc[p]);
    }
}

// ---------------------------------------------------------------------------
// MFMA 3x3 conv 64->64, bf16 NHWC in, optional fp32 resid, fp32/bf16 outs.
// Tile 16 wide x 8 tall, halo 18x10=180 px, LDS stride 72 shorts (25.9 KB).
// Block 256 = 4 waves; wave w: M-tile w (px w*32..+31) x 2 N-tiles.
// Grid 512 (2 blocks/CU). B streamed via depth-6 register prefetch queue.
// ---------------------------------------------------------------------------
__global__ __launch_bounds__(256, 2) void conv3x3_mfma(const unsigned short* __restrict__ in,
                                                       const unsigned short* __restrict__ wp,
                                                       const float* __restrict__ bias,
                                                       const float* __restrict__ residF,
                                                       float* __restrict__ outF,
                                                       unsigned short* __restrict__ outB,
                                                       int act) {
    __shared__ unsigned short sm[180 * 72];
    int tid = threadIdx.x;
    int bid = blockIdx.x;
    int b = bid >> 5;
    int rem = bid & 31;
    int ty = rem >> 2, tx = rem & 3;
    const unsigned short* inb = in + (size_t)b * 262144;

    int lane = tid & 63, w = tid >> 6;
    const unsigned short* bp = wp + (size_t)lane * 8;

    // B prefetch queue: issue before staging so loads overlap the halo copy
    bh8 q0[6], q1[6];
#pragma unroll
    for (int i = 0; i < 6; ++i) {
        q0[i] = *(const bh8*)&bp[(size_t)i * 1024];
        q1[i] = *(const bh8*)&bp[(size_t)i * 1024 + 512];
    }

    for (int i = tid; i < 1440; i += 256) {
        int px = i >> 3, c8 = i & 7;
        int hy = px / 18, hx = px - hy * 18;
        int row = ty * 8 + hy - 1, col = tx * 16 + hx - 1;
        uint4 u = make_uint4(0u, 0u, 0u, 0u);
        if (row >= 0 && row < 64 && col >= 0 && col < 64)
            u = *(const uint4*)(inb + (((size_t)row * 64 + col) * 64 + c8 * 8));
        *(uint4*)&sm[px * 72 + c8 * 8] = u;
    }
    __syncthreads();

    int l31 = lane & 31, kg8 = (lane >> 5) * 8;
    int p0 = w * 32 + l31;
    int ly0 = p0 >> 4, lx0 = p0 & 15;

    f16acc a0 = {0,0,0,0,0,0,0,0,0,0,0,0,0,0,0,0};
    f16acc a1 = a0;

#pragma unroll
    for (int c = 0; c < 36; ++c) {
        int t = c >> 2, cc = c & 3;
        int tyt = t / 3, txt = t - tyt * 3;
        int base = ((ly0 + tyt) * 18 + lx0 + txt) * 72 + cc * 16 + kg8;
        bh8 A = *(const bh8*)&sm[base];
        bh8 B0 = q0[c % 6], B1 = q1[c % 6];
        if (c + 6 < 36) {
            q0[c % 6] = *(const bh8*)&bp[(size_t)(c + 6) * 1024];
            q1[c % 6] = *(const bh8*)&bp[(size_t)(c + 6) * 1024 + 512];
        }
        MFMA32(a0, A, B0);
        MFMA32(a1, A, B1);
    }

    float bias0 = bias[l31], bias1 = bias[32 + l31];
    int hi = lane >> 5;
    size_t outb = (size_t)b * 262144;
#pragma unroll
    for (int r = 0; r < 16; ++r) {
        int rowm = (r & 3) + 8 * (r >> 2) + 4 * hi;
        int m = w * 32 + rowm;
        int gy = ty * 8 + (m >> 4), gx = tx * 16 + (m & 15);
        size_t i0 = outb + (((size_t)gy * 64 + gx) * 64);
        float v0 = a0[r] + bias0, v1 = a1[r] + bias1;
        if (residF) {
            v0 += residF[i0 + l31];
            v1 += residF[i0 + 32 + l31];
        }
        if (act) { v0 = lrelu_f(v0); v1 = lrelu_f(v1); }
        if (outF) {
            outF[i0 + l31] = v0;
            outF[i0 + 32 + l31] = v1;
        }
        if (outB) {
            outB[i0 + l31] = f2bf(v0);
            outB[i0 + 32 + l31] = f2bf(v1);
        }
    }
}

// ---------------------------------------------------------------------------
// Fused DA_conv (MFMA): bf16 in -> LDS halo -> depthwise 3x3 (fp32 math,
// dword-vectorized: thread = (ch-pair, row)) -> mid LDS bf16 -> 1x1 MFMA
// (B in LDS) -> +cb + in*att -> lrelu -> bf16 out.
// Tile 16x8, halo 180 px. Grid 512 (2 blocks/CU). LDS 52.3 KB.
// ---------------------------------------------------------------------------
__global__ __launch_bounds__(256, 2) void da_mfma(const unsigned short* __restrict__ in,
                                                  const unsigned short* __restrict__ wp,
                                                  const float* __restrict__ cb,
                                                  const float* __restrict__ kerT,
                                                  const float* __restrict__ attv,
                                                  unsigned short* __restrict__ out) {
    __shared__ unsigned short sm[180 * 72];
    __shared__ unsigned short mid[128 * 72];
    __shared__ unsigned short bds[4096];
    int tid = threadIdx.x;
    int bid = blockIdx.x;
    int b = bid >> 5;
    int rem = bid & 31;
    int ty = rem >> 2, tx = rem & 3;
    const unsigned short* inb = in + (size_t)b * 262144;

    for (int i = tid; i < 1440; i += 256) {
        int px = i >> 3, c8 = i & 7;
        int hy = px / 18, hx = px - hy * 18;
        int row = ty * 8 + hy - 1, col = tx * 16 + hx - 1;
        uint4 u = make_uint4(0u, 0u, 0u, 0u);
        if (row >= 0 && row < 64 && col >= 0 && col < 64)
            u = *(const uint4*)(inb + (((size_t)row * 64 + col) * 64 + c8 * 8));
        *(uint4*)&sm[px * 72 + c8 * 8] = u;
    }
#pragma unroll
    for (int i = 0; i < 2; ++i) {
        int idx = i * 256 + tid;
        *(uint4*)&bds[idx * 8] = *(const uint4*)&wp[idx * 8];
    }
    __syncthreads();

    // depthwise from LDS: thread = (c2 = ch pair, q = row), dword reads
    {
        int c2 = tid & 31, q = tid >> 5;
        const float* kb = kerT + (size_t)b * 576 + 2 * c2;
        float ka[9], kbv[9];
#pragma unroll
        for (int t = 0; t < 9; ++t) {
            ka[t] = kb[t * 64];
            kbv[t] = kb[t * 64 + 1];
        }
        float m0[16], m1[16];
#pragma unroll
        for (int xx = 0; xx < 16; ++xx) { m0[xx] = 0.f; m1[xx] = 0.f; }
#pragma unroll
        for (int ky = 0; ky < 3; ++ky) {
            int hr = q + ky;
            float va[18], vb[18];
#pragma unroll
            for (int i = 0; i < 18; ++i) {
                unsigned u = *(const unsigned*)&sm[(hr * 18 + i) * 72 + 2 * c2];
                va[i] = bf2f((unsigned short)(u & 0xffffu));
                vb[i] = bf2f((unsigned short)(u >> 16));
            }
            float k0a = ka[ky * 3], k1a = ka[ky * 3 + 1], k2a = ka[ky * 3 + 2];
            float k0b = kbv[ky * 3], k1b = kbv[ky * 3 + 1], k2b = kbv[ky * 3 + 2];
#pragma unroll
            for (int xx = 0; xx < 16; ++xx) {
                m0[xx] += k0a * va[xx] + k1a * va[xx + 1] + k2a * va[xx + 2];
                m1[xx] += k0b * vb[xx] + k1b * vb[xx + 1] + k2b * vb[xx + 2];
            }
        }
#pragma unroll
        for (int xx = 0; xx < 16; ++xx) {
            unsigned u = (unsigned)f2bf(lrelu_f(m0[xx])) |
                         ((unsigned)f2bf(lrelu_f(m1[xx])) << 16);
            *(unsigned*)&mid[(q * 16 + xx) * 72 + 2 * c2] = u;
        }
    }
    __syncthreads();

    // 1x1 MFMA, K=64
    int lane = tid & 63, w = tid >> 6;
    int l31 = lane & 31, kg8 = (lane >> 5) * 8;
    int base = (w * 32 + l31) * 72 + kg8;

    f16acc a0 = {0,0,0,0,0,0,0,0,0,0,0,0,0,0,0,0};
    f16acc a1 = a0;
#pragma unroll
    for (int cc = 0; cc < 4; ++cc) {
        bh8 A = *(const bh8*)&mid[base + cc * 16];
        bh8 B0 = *(const bh8*)&bds[((cc * 2 + 0) * 64 + lane) * 8];
        bh8 B1 = *(const bh8*)&bds[((cc * 2 + 1) * 64 + lane) * 8];
        MFMA32(a0, A, B0);
        MFMA32(a1, A, B1);
    }

    float cb0 = cb[l31], cb1 = cb[32 + l31];
    float at0 = attv[b * 64 + l31], at1 = attv[b * 64 + 32 + l31];
    int hi = lane >> 5;
    size_t outb = (size_t)b * 262144;
#pragma unroll
    for (int r = 0; r < 16; ++r) {
        int rowm = (r & 3) + 8 * (r >> 2) + 4 * hi;
        int m = w * 32 + rowm;
        int gy = ty * 8 + (m >> 4), gx = tx * 16 + (m & 15);
        size_t i0 = outb + (((size_t)gy * 64 + gx) * 64);
        float v0 = a0[r] + cb0 + bf2f(in[i0 + l31]) * at0;
        float v1 = a1[r] + cb1 + bf2f(in[i0 + 32 + l31]) * at1;
        out[i0 + l31] = f2bf(lrelu_f(v0));
        out[i0 + 32 + l31] = f2bf(lrelu_f(v1));
    }
}

// ---------------------------------------------------------------------------
// Up conv 64->256 (MFMA) + fused pixel shuffle. bf16 in/out.
// Tile 8x8 px, halo 10x10. Wave w: co [w*64, w*64+64). Grid 1024.
// B streamed via depth-4 register prefetch queue.
// ---------------------------------------------------------------------------
__global__ __launch_bounds__(256, 2) void up_mfma(const unsigned short* __restrict__ in,
                                                  const unsigned short* __restrict__ wp,
                                                  const float* __restrict__ bias,
                                                  unsigned short* __restrict__ shuf) {
    __shared__ unsigned short sm[100 * 72];
    int tid = threadIdx.x;
    int bid = blockIdx.x;
    int b = bid >> 6;
    int t6 = bid & 63;
    int ty = t6 >> 3, tx = t6 & 7;
    const unsigned short* inb = in + (size_t)b * 262144;

    int lane = tid & 63, w = tid >> 6;
    const unsigned short* bp = wp + (size_t)(w * 2) * 512 + (size_t)lane * 8;

    bh8 q0[4], q1[4];
#pragma unroll
    for (int i = 0; i < 4; ++i) {
        q0[i] = *(const bh8*)&bp[(size_t)i * 4096];
        q1[i] = *(const bh8*)&bp[(size_t)i * 4096 + 512];
    }

    for (int i = tid; i < 800; i += 256) {
        int px = i >> 3, c8 = i & 7;
        int hy = px / 10, hx = px - hy * 10;
        int row = ty * 8 + hy - 1, col = tx * 8 + hx - 1;
        uint4 u = make_uint4(0u, 0u, 0u, 0u);
        if (row >= 0 && row < 64 && col >= 0 && col < 64)
            u = *(const uint4*)(inb + (((size_t)row * 64 + col) * 64 + c8 * 8));
        *(uint4*)&sm[px * 72 + c8 * 8] = u;
    }
    __syncthreads();

    int l31 = lane & 31, kg8 = (lane >> 5) * 8;
    int ly0 = l31 >> 3, lx0 = l31 & 7;

    f16acc a00 = {0,0,0,0,0,0,0,0,0,0,0,0,0,0,0,0};
    f16acc a01 = a00, a10 = a00, a11 = a00;

#pragma unroll
    for (int c = 0; c < 36; ++c) {
        int t = c >> 2, cc = c & 3;
        int tyt = t / 3, txt = t - tyt * 3;
        int base0 = ((ly0 + tyt) * 10 + lx0 + txt) * 72 + cc * 16 + kg8;
        int base1 = base0 + 2880;  // +32 px = +4 halo rows
        bh8 A0 = *(const bh8*)&sm[base0];
        bh8 A1 = *(const bh8*)&sm[base1];
        bh8 B0 = q0[c % 4], B1 = q1[c % 4];
        if (c + 4 < 36) {
            q0[c % 4] = *(const bh8*)&bp[(size_t)(c + 4) * 4096];
            q1[c % 4] = *(const bh8*)&bp[(size_t)(c + 4) * 4096 + 512];
        }
        MFMA32(a00, A0, B0);
        MFMA32(a01, A0, B1);
        MFMA32(a10, A1, B0);
        MFMA32(a11, A1, B1);
    }

    int co0 = w * 64 + l31, co1 = co0 + 32;
    float bias0 = bias[co0], bias1 = bias[co1];
    int ch0 = co0 >> 2, r10 = (co0 >> 1) & 1, r20 = co0 & 1;
    int ch1 = co1 >> 2, r11 = (co1 >> 1) & 1, r21 = co1 & 1;
    int hi = lane >> 5;
#pragma unroll
    for (int r = 0; r < 16; ++r) {
        int rowm = (r & 3) + 8 * (r >> 2) + 4 * hi;
#pragma unroll
        for (int mt = 0; mt < 2; ++mt) {
            int m = mt * 32 + rowm;
            int y = ty * 8 + (m >> 3), x = tx * 8 + (m & 7);
            float va = (mt == 0) ? a00[r] : a10[r];
            float vb = (mt == 0) ? a01[r] : a11[r];
            shuf[(((size_t)b * 128 + 2 * y + r10) * 128 + 2 * x + r20) * 64 + ch0] = f2bf(va + bias0);
            shuf[(((size_t)b * 128 + 2 * y + r11) * 128 + 2 * x + r21) * 64 + ch1] = f2bf(vb + bias1);
        }
    }
}

// ---------------------------------------------------------------------------
// Tail conv 64->3 as MFMA, N padded to 32. shuf bf16 NHWC -> out NCHW fp32.
// Tile 16x16, halo 18x18. Grid 1024.
// ---------------------------------------------------------------------------
__global__ __launch_bounds__(256) void tail_mfma(const unsigned short* __restrict__ shuf,
                                                 const unsigned short* __restrict__ wp,
                                                 const float* __restrict__ bias,
                                                 float* __restrict__ outp) {
    __shared__ unsigned short sm[324 * 72];
    int tid = threadIdx.x;
    int bid = blockIdx.x;
    int b = bid >> 6;
    int rem = bid & 63;
    int ty = rem >> 3, tx = rem & 7;
    const unsigned short* sb = shuf + (size_t)b * 128 * 128 * 64;

    for (int i = tid; i < 2592; i += 256) {
        int px = i >> 3, c8 = i & 7;
        int hy = px / 18, hx = px - hy * 18;
        int row = ty * 16 + hy - 1, col = tx * 16 + hx - 1;
        uint4 u = make_uint4(0u, 0u, 0u, 0u);
        if (row >= 0 && row < 128 && col >= 0 && col < 128)
            u = *(const uint4*)(sb + (((size_t)row * 128 + col) * 64 + c8 * 8));
        *(uint4*)&sm[px * 72 + c8 * 8] = u;
    }
    __syncthreads();

    int lane = tid & 63, w = tid >> 6;
    int l31 = lane & 31, kg8 = (lane >> 5) * 8;
    int mbase = w * 64;
    int p0 = mbase + l31;
    int ly0 = p0 >> 4, lx0 = p0 & 15;

    f16acc a0 = {0,0,0,0,0,0,0,0,0,0,0,0,0,0,0,0};
    f16acc a1 = a0;

#pragma unroll
    for (int t = 0; t < 9; ++t) {
        int tyt = t / 3, txt = t - tyt * 3;
        int base0 = ((ly0 + tyt) * 18 + lx0 + txt) * 72 + kg8;
        int base1 = base0 + 2592;
#pragma unroll
        for (int cc = 0; cc < 4; ++cc) {
            int c = t * 4 + cc;
            bh8 A0 = *(const bh8*)&sm[base0 + cc * 16];
            bh8 A1 = *(const bh8*)&sm[base1 + cc * 16];
            bh8 B = *(const bh8*)&wp[((size_t)c * 64 + lane) * 8];
            MFMA32(a0, A0, B);
            MFMA32(a1, A1, B);
        }
    }

    if (l31 < 3) {
        float bv = bias[l31];
        int hi = lane >> 5;
        size_t ob = ((size_t)b * 3 + l31) * 16384;
#pragma unroll
        for (int r = 0; r < 16; ++r) {
            int rowm = (r & 3) + 8 * (r >> 2) + 4 * hi;
            int m0 = mbase + rowm;
            int gy0 = ty * 16 + (m0 >> 4), gx0 = tx * 16 + (m0 & 15);
            outp[ob + (size_t)gy0 * 128 + gx0] = a0[r] + bv;
            int m1 = m0 + 32;
            int gy1 = ty * 16 + (m1 >> 4), gx1 = tx * 16 + (m1 & 15);
            outp[ob + (size_t)gy1 * 128 + gx1] = a1[r] + bv;
        }
    }
}

// ---------------------------------------------------------------------------
extern "C" void kernel_launch(void* const* d_in, const int* in_sizes, int n_in,
                              void* d_out, int out_size, void* d_ws, size_t ws_size,
                              hipStream_t stream) {
    const float* x      = (const float*)d_in[0];
    const float* k_v    = (const float*)d_in[1];
    const float* head_w = (const float*)d_in[2];
    const float* head_b = (const float*)d_in[3];
    const float* comp_w = (const float*)d_in[4];
    const float* da_kw1 = (const float*)d_in[5];
    const float* da_kw2 = (const float*)d_in[6];
    const float* da_cw  = (const float*)d_in[7];
    const float* da_cb  = (const float*)d_in[8];
    const float* ca_w1  = (const float*)d_in[9];
    const float* ca_w2  = (const float*)d_in[10];
    const float* dab_cw = (const float*)d_in[11];
    const float* dab_cb = (const float*)d_in[12];
    const float* grp_w  = (const float*)d_in[13];
    const float* grp_b  = (const float*)d_in[14];
    const float* body_w = (const float*)d_in[15];
    const float* body_b = (const float*)d_in[16];
    const float* up_w   = (const float*)d_in[17];
    const float* up_b   = (const float*)d_in[18];
    const float* tail_w = (const float*)d_in[19];
    const float* tail_b = (const float*)d_in[20];

    char* base = (char*)d_ws;
    auto alloc = [&](size_t bytes) -> char* {
        char* p = base;
        base += (bytes + 255) & ~(size_t)255;
        return p;
    };
    unsigned short* wp_dab  = (unsigned short*)alloc((size_t)50 * 36864 * 2);
    unsigned short* wp_grp  = (unsigned short*)alloc((size_t)5 * 36864 * 2);
    unsigned short* wp_body = (unsigned short*)alloc((size_t)36864 * 2);
    unsigned short* wp_up   = (unsigned short*)alloc((size_t)147456 * 2);
    unsigned short* wp_da   = (unsigned short*)alloc((size_t)50 * 4096 * 2);
    unsigned short* wp_tail = (unsigned short*)alloc((size_t)18432 * 2);
    float* wT_head = (float*)alloc(1728 * 4);
    float* kvbuf   = (float*)alloc(1024 * 4);
    float* ker_all = (float*)alloc((size_t)460800 * 4);
    float* att_all = (float*)alloc((size_t)51200 * 4);
    const size_t ACT = (size_t)16 * 64 * 64 * 64;
    float* x0 = (float*)alloc(ACT * 4);
    float* rA = (float*)alloc(ACT * 4);
    float* rB = (float*)alloc(ACT * 4);
    float* rC = (float*)alloc(ACT * 4);
    unsigned short* sA = (unsigned short*)alloc(ACT * 2);
    unsigned short* sB = (unsigned short*)alloc(ACT * 2);
    unsigned short* sC = (unsigned short*)alloc(ACT * 2);
    unsigned short* t0 = (unsigned short*)alloc(ACT * 2);
    unsigned short* t1 = (unsigned short*)alloc(ACT * 2);
    unsigned short* shuf = (unsigned short*)alloc((size_t)16 * 128 * 128 * 64 * 2);

    pack3x3<<<900, 256, 0, stream>>>(dab_cw, wp_dab, 50);
    pack3x3<<<90, 256, 0, stream>>>(grp_w, wp_grp, 5);
    pack3x3<<<18, 256, 0, stream>>>(body_w, wp_body, 1);
    pack_da<<<100, 256, 0, stream>>>(da_cw, wp_da, 50);
    pack_up<<<72, 256, 0, stream>>>(up_w, wp_up);
    pack_tail<<<9, 256, 0, stream>>>(tail_w, wp_tail);
    transpose_w<<<7, 256, 0, stream>>>(head_w, wT_head, 1, 64, 27);

    kv_kernel<<<16, 64, 0, stream>>>(k_v, comp_w, kvbuf);
    kerprep<<<800, 64, 0, stream>>>(kvbuf, da_kw1, da_kw2, ca_w1, ca_w2, ker_all, att_all);

    head_conv<<<2048, 256, 0, stream>>>(x, wT_head, head_b, x0, rA, sA);

    for (int g = 0; g < 5; ++g) {
        float* curF = rA;
        unsigned short* curS = sA;
        for (int n = 0; n < 5; ++n) {
            int l0 = (g * 5 + n) * 2, l1 = l0 + 1;
            da_mfma<<<512, 256, 0, stream>>>(curS, wp_da + (size_t)l0 * 4096,
                                             da_cb + (size_t)l0 * 64, ker_all + (size_t)l0 * 9216,
                                             att_all + (size_t)l0 * 1024, t0);
            conv3x3_mfma<<<512, 256, 0, stream>>>(t0, wp_dab + (size_t)l0 * 36864,
                                                  dab_cb + (size_t)l0 * 64, nullptr,
                                                  nullptr, t1, 1);
            da_mfma<<<512, 256, 0, stream>>>(t1, wp_da + (size_t)l1 * 4096,
                                             da_cb + (size_t)l1 * 64, ker_all + (size_t)l1 * 9216,
                                             att_all + (size_t)l1 * 1024, t0);
            float* outF = (curF == rB) ? rC : rB;
            unsigned short* outS = (curS == sB) ? sC : sB;
            conv3x3_mfma<<<512, 256, 0, stream>>>(t0, wp_dab + (size_t)l1 * 36864,
                                                  dab_cb + (size_t)l1 * 64, curF,
                                                  outF, outS, 0);
            curF = outF;
            curS = outS;
        }
        // after 5 DABs cur == rB/sB; spare is rC/sC
        conv3x3_mfma<<<512, 256, 0, stream>>>(curS, wp_grp + (size_t)g * 36864,
                                              grp_b + (size_t)g * 64, rA, rC, sC, 0);
        // rotate: new group input = rC
        float* tf = rA; rA = rC; rC = tf;
        unsigned short* ts = sA; sA = sC; sC = ts;
    }
    conv3x3_mfma<<<512, 256, 0, stream>>>(sA, wp_body, body_b, x0, nullptr, t0, 0);

    up_mfma<<<1024, 256, 0, stream>>>(t0, wp_up, up_b, shuf);
    tail_mfma<<<1024, 256, 0, stream>>>(shuf, wp_tail, tail_b, (float*)d_out);
}

// Round 7
// 1524.367 us; speedup vs baseline: 1.2900x; 1.0063x over previous
//
#include <hip/hip_runtime.h>
#include <math.h>

#define DEV __device__ __forceinline__

DEV float lrelu_f(float v) { return v > 0.f ? v : 0.1f * v; }

DEV unsigned short f2bf(float f) {
    unsigned u = __builtin_bit_cast(unsigned, f);
    unsigned r = u + 0x7FFFu + ((u >> 16) & 1u);
    return (unsigned short)(r >> 16);
}

DEV float bf2f(unsigned short s) {
    return __builtin_bit_cast(float, (unsigned)s << 16);
}

typedef __attribute__((ext_vector_type(8))) short bh8;
typedef __attribute__((ext_vector_type(16))) float f16acc;

#define MFMA32(acc, a, b) acc = __builtin_amdgcn_mfma_f32_32x32x16_bf16(a, b, acc, 0, 0, 0)

// ---------------------------------------------------------------------------
// Weight transpose: src [L][O][KK] -> dst [L][KK][O]  (head only)
// ---------------------------------------------------------------------------
__global__ void transpose_w(const float* __restrict__ src, float* __restrict__ dst,
                            int L, int O, int KK) {
    int idx = blockIdx.x * 256 + threadIdx.x;
    int tot = L * O * KK;
    if (idx >= tot) return;
    int l = idx / (O * KK);
    int r = idx - l * (O * KK);
    int o = r / KK;
    int k = r - o * KK;
    dst[((size_t)l * KK + k) * O + o] = src[idx];
}

// ---------------------------------------------------------------------------
// Pack 3x3 conv weights [L][64 o][64 cin][3][3] -> frag layout
// [L][36 chunk][2 nt][64 lane][8 j] bf16, k = tap*64+cin, o = nt*32+(lane&31)
// ---------------------------------------------------------------------------
__global__ void pack3x3(const float* __restrict__ src, unsigned short* __restrict__ dst, int L) {
    int idx = blockIdx.x * 256 + threadIdx.x;
    if (idx >= L * 4608) return;
    int l = idx / 4608;
    int r = idx - l * 4608;
    int c = r >> 7;
    int rr = r & 127;
    int nt = rr >> 6, lane = rr & 63;
    int o = nt * 32 + (lane & 31);
    int kg = lane >> 5;
    unsigned short v[8];
#pragma unroll
    for (int j = 0; j < 8; ++j) {
        int k = c * 16 + kg * 8 + j;
        int t = k >> 6, cin = k & 63;
        v[j] = f2bf(src[(((size_t)l * 64 + o) * 64 + cin) * 9 + t]);
    }
    uint4 u;
    u.x = v[0] | ((unsigned)v[1] << 16);
    u.y = v[2] | ((unsigned)v[3] << 16);
    u.z = v[4] | ((unsigned)v[5] << 16);
    u.w = v[6] | ((unsigned)v[7] << 16);
    *(uint4*)(dst + (size_t)idx * 8) = u;
}

// ---------------------------------------------------------------------------
// Pack da 1x1 weights [L][64 o][64 cin] -> [L][4 chunk][2 nt][64][8] bf16
// ---------------------------------------------------------------------------
__global__ void pack_da(const float* __restrict__ src, unsigned short* __restrict__ dst, int L) {
    int idx = blockIdx.x * 256 + threadIdx.x;
    if (idx >= L * 512) return;
    int l = idx >> 9;
    int r = idx & 511;
    int c = r >> 7;
    int rr = r & 127;
    int nt = rr >> 6, lane = rr & 63;
    int o = nt * 32 + (lane & 31);
    int kg = lane >> 5;
    unsigned short v[8];
#pragma unroll
    for (int j = 0; j < 8; ++j) {
        int cin = c * 16 + kg * 8 + j;
        v[j] = f2bf(src[((size_t)l * 64 + o) * 64 + cin]);
    }
    uint4 u;
    u.x = v[0] | ((unsigned)v[1] << 16);
    u.y = v[2] | ((unsigned)v[3] << 16);
    u.z = v[4] | ((unsigned)v[5] << 16);
    u.w = v[6] | ((unsigned)v[7] << 16);
    *(uint4*)(dst + (size_t)idx * 8) = u;
}

// ---------------------------------------------------------------------------
// Pack up conv weights [256 o][64 cin][3][3] -> [36 chunk][8 nt][64][8] bf16
// ---------------------------------------------------------------------------
__global__ void pack_up(const float* __restrict__ src, unsigned short* __restrict__ dst) {
    int idx = blockIdx.x * 256 + threadIdx.x;
    if (idx >= 18432) return;
    int c = idx >> 9;
    int nt = (idx >> 6) & 7;
    int lane = idx & 63;
    int o = nt * 32 + (lane & 31);
    int kg = lane >> 5;
    unsigned short v[8];
#pragma unroll
    for (int j = 0; j < 8; ++j) {
        int k = c * 16 + kg * 8 + j;
        int t = k >> 6, cin = k & 63;
        v[j] = f2bf(src[((size_t)o * 64 + cin) * 9 + t]);
    }
    uint4 u;
    u.x = v[0] | ((unsigned)v[1] << 16);
    u.y = v[2] | ((unsigned)v[3] << 16);
    u.z = v[4] | ((unsigned)v[5] << 16);
    u.w = v[6] | ((unsigned)v[7] << 16);
    *(uint4*)(dst + (size_t)idx * 8) = u;
}

// ---------------------------------------------------------------------------
// Pack tail conv weights [3 o][64 cin][3][3] -> [36 chunk][64 lane][8] bf16
// N padded 3 -> 32 with zeros.
// ---------------------------------------------------------------------------
__global__ void pack_tail(const float* __restrict__ src, unsigned short* __restrict__ dst) {
    int idx = blockIdx.x * 256 + threadIdx.x;
    if (idx >= 2304) return;
    int c = idx >> 6;
    int lane = idx & 63;
    int o = lane & 31;
    int kg = lane >> 5;
    unsigned short v[8];
#pragma unroll
    for (int j = 0; j < 8; ++j) {
        int k = c * 16 + kg * 8 + j;
        int t = k >> 6, cin = k & 63;
        v[j] = (o < 3) ? f2bf(src[((size_t)o * 64 + cin) * 9 + t]) : (unsigned short)0;
    }
    uint4 u;
    u.x = v[0] | ((unsigned)v[1] << 16);
    u.y = v[2] | ((unsigned)v[3] << 16);
    u.z = v[4] | ((unsigned)v[5] << 16);
    u.w = v[6] | ((unsigned)v[7] << 16);
    *(uint4*)(dst + (size_t)idx * 8) = u;
}

// ---------------------------------------------------------------------------
// kv = lrelu(k_v @ comp_w.T)
// ---------------------------------------------------------------------------
__global__ void kv_kernel(const float* __restrict__ kvin, const float* __restrict__ comp_w,
                          float* __restrict__ kv) {
    int b = blockIdx.x, c = threadIdx.x;
    const float* a = kvin + b * 256;
    const float* w = comp_w + c * 256;
    float s = 0.f;
    for (int m = 0; m < 256; ++m) s += a[m] * w[m];
    kv[b * 64 + c] = lrelu_f(s);
}

// ---------------------------------------------------------------------------
// Per-(layer,batch) dynamic kernel + CA attention precompute.
// ---------------------------------------------------------------------------
__global__ void kerprep(const float* __restrict__ kv, const float* __restrict__ kw1,
                        const float* __restrict__ kw2, const float* __restrict__ caw1,
                        const float* __restrict__ caw2, float* __restrict__ ker_all,
                        float* __restrict__ att_all) {
    int l = blockIdx.x >> 4;
    int b = blockIdx.x & 15;
    int c = threadIdx.x;
    __shared__ float kvb[64];
    __shared__ float t1[64];
    __shared__ float a1[8];
    kvb[c] = kv[b * 64 + c];
    __syncthreads();
    {
        const float* w1 = kw1 + (size_t)l * 4096 + c * 64;
        float s = 0.f;
        for (int j = 0; j < 64; ++j) s += kvb[j] * w1[j];
        t1[c] = lrelu_f(s);
    }
    if (c < 8) {
        const float* cw1 = caw1 + (size_t)l * 512 + c * 64;
        float s = 0.f;
        for (int j = 0; j < 64; ++j) s += kvb[j] * cw1[j];
        a1[c] = lrelu_f(s);
    }
    __syncthreads();
    const float* w2 = kw2 + (size_t)l * 576 * 64;
    for (int t = 0; t < 9; ++t) {
        const float* row = w2 + (size_t)(c * 9 + t) * 64;
        float s = 0.f;
        for (int j = 0; j < 64; ++j) s += t1[j] * row[j];
        ker_all[(((size_t)l * 16 + b) * 9 + t) * 64 + c] = s;
    }
    {
        const float* c2 = caw2 + (size_t)l * 512 + c * 8;
        float s = 0.f;
        for (int r = 0; r < 8; ++r) s += a1[r] * c2[r];
        att_all[((size_t)l * 16 + b) * 64 + c] = 1.f / (1.f + expf(-s));
    }
}

// ---------------------------------------------------------------------------
// Head conv: x NCHW [16,3,64,64] fp32 -> x0,res fp32 + shadow bf16 (NHWC)
// ---------------------------------------------------------------------------
__global__ __launch_bounds__(256) void head_conv(const float* __restrict__ x,
                                                 const float* __restrict__ wt,
                                                 const float* __restrict__ bias,
                                                 float* __restrict__ x0,
                                                 float* __restrict__ res,
                                                 unsigned short* __restrict__ resS) {
    int t = threadIdx.x;
    int co = t & 63, q = t >> 6;
    int bid = blockIdx.x;
    int b = bid >> 7;
    int rem = bid & 127;
    int y = rem >> 1;
    int xs = (rem & 1) * 32 + q * 8;

    float bv = bias[co];
    float acc[8];
#pragma unroll
    for (int p = 0; p < 8; ++p) acc[p] = bv;

    int coff[10];
    bool cok[10];
#pragma unroll
    for (int i = 0; i < 10; ++i) {
        int col = xs - 1 + i;
        cok[i] = (col >= 0) && (col < 64);
        coff[i] = cok[i] ? col : 0;
    }
    for (int cin = 0; cin < 3; ++cin) {
#pragma unroll
        for (int ky = 0; ky < 3; ++ky) {
            int row = y + ky - 1;
            bool rok = (row >= 0) && (row < 64);
            const float* rp = x + ((size_t)(b * 3 + cin) * 64 + (rok ? row : 0)) * 64;
            float v[10];
#pragma unroll
            for (int i = 0; i < 10; ++i) v[i] = (rok && cok[i]) ? rp[coff[i]] : 0.f;
            const float* wp = wt + ((cin * 3 + ky) * 3) * 64 + co;
            float w0 = wp[0], w1 = wp[64], w2 = wp[128];
#pragma unroll
            for (int p = 0; p < 8; ++p) acc[p] += w0 * v[p] + w1 * v[p + 1] + w2 * v[p + 2];
        }
    }
    size_t ob = (((size_t)b * 64 + y) * 64 + xs) * 64 + co;
#pragma unroll
    for (int p = 0; p < 8; ++p) {
        x0[ob + (size_t)p * 64] = acc[p];
        res[ob + (size_t)p * 64] = acc[p];
        resS[ob + (size_t)p * 64] = f2bf(acc[p]);
    }
}

// ---------------------------------------------------------------------------
// MFMA 3x3 conv 64->64 (group tail / body). Same as round 6.
// Tile 16x8, halo 18x10, grid 512, B depth-6 register queue.
// ---------------------------------------------------------------------------
__global__ __launch_bounds__(256, 2) void conv3x3_mfma(const unsigned short* __restrict__ in,
                                                       const unsigned short* __restrict__ wp,
                                                       const float* __restrict__ bias,
                                                       const float* __restrict__ residF,
                                                       float* __restrict__ outF,
                                                       unsigned short* __restrict__ outB,
                                                       int act) {
    __shared__ unsigned short sm[180 * 72];
    int tid = threadIdx.x;
    int bid = blockIdx.x;
    int b = bid >> 5;
    int rem = bid & 31;
    int ty = rem >> 2, tx = rem & 3;
    const unsigned short* inb = in + (size_t)b * 262144;

    int lane = tid & 63, w = tid >> 6;
    const unsigned short* bp = wp + (size_t)lane * 8;

    bh8 q0[6], q1[6];
#pragma unroll
    for (int i = 0; i < 6; ++i) {
        q0[i] = *(const bh8*)&bp[(size_t)i * 1024];
        q1[i] = *(const bh8*)&bp[(size_t)i * 1024 + 512];
    }

    for (int i = tid; i < 1440; i += 256) {
        int px = i >> 3, c8 = i & 7;
        int hy = px / 18, hx = px - hy * 18;
        int row = ty * 8 + hy - 1, col = tx * 16 + hx - 1;
        uint4 u = make_uint4(0u, 0u, 0u, 0u);
        if (row >= 0 && row < 64 && col >= 0 && col < 64)
            u = *(const uint4*)(inb + (((size_t)row * 64 + col) * 64 + c8 * 8));
        *(uint4*)&sm[px * 72 + c8 * 8] = u;
    }
    __syncthreads();

    int l31 = lane & 31, kg8 = (lane >> 5) * 8;
    int p0 = w * 32 + l31;
    int ly0 = p0 >> 4, lx0 = p0 & 15;

    f16acc a0 = {0,0,0,0,0,0,0,0,0,0,0,0,0,0,0,0};
    f16acc a1 = a0;

#pragma unroll
    for (int c = 0; c < 36; ++c) {
        int t = c >> 2, cc = c & 3;
        int tyt = t / 3, txt = t - tyt * 3;
        int base = ((ly0 + tyt) * 18 + lx0 + txt) * 72 + cc * 16 + kg8;
        bh8 A = *(const bh8*)&sm[base];
        bh8 B0 = q0[c % 6], B1 = q1[c % 6];
        if (c + 6 < 36) {
            q0[c % 6] = *(const bh8*)&bp[(size_t)(c + 6) * 1024];
            q1[c % 6] = *(const bh8*)&bp[(size_t)(c + 6) * 1024 + 512];
        }
        MFMA32(a0, A, B0);
        MFMA32(a1, A, B1);
    }

    float bias0 = bias[l31], bias1 = bias[32 + l31];
    int hi = lane >> 5;
    size_t outb = (size_t)b * 262144;
#pragma unroll
    for (int r = 0; r < 16; ++r) {
        int rowm = (r & 3) + 8 * (r >> 2) + 4 * hi;
        int m = w * 32 + rowm;
        int gy = ty * 8 + (m >> 4), gx = tx * 16 + (m & 15);
        size_t i0 = outb + (((size_t)gy * 64 + gx) * 64);
        float v0 = a0[r] + bias0, v1 = a1[r] + bias1;
        if (residF) {
            v0 += residF[i0 + l31];
            v1 += residF[i0 + 32 + l31];
        }
        if (act) { v0 = lrelu_f(v0); v1 = lrelu_f(v1); }
        if (outF) {
            outF[i0 + l31] = v0;
            outF[i0 + 32 + l31] = v1;
        }
        if (outB) {
            outB[i0 + l31] = f2bf(v0);
            outB[i0 + 32 + l31] = f2bf(v1);
        }
    }
}

// ---------------------------------------------------------------------------
// Fused DAB half: out = conv3x3( lrelu(da_conv(in)) ) [+resid][lrelu?]
// da_conv(in) = lrelu( 1x1(lrelu(dw3x3(in,ker))) + cb + in*att )
// Tile 16x8 out, halo 2: sin 20x12 (stride 72), mid (dw->da-out in place)
// 18x10 (192-px buffer, stride 72). LDS 62 KB -> 2 blocks/CU. Grid 512.
// Out-of-image mid px forced to ZERO (conv zero-pad semantics).
// ---------------------------------------------------------------------------
__global__ __launch_bounds__(256, 2) void dab_mfma(const unsigned short* __restrict__ in,
                                                   const unsigned short* __restrict__ wda,
                                                   const float* __restrict__ cb,
                                                   const float* __restrict__ kerT,
                                                   const float* __restrict__ attv,
                                                   const unsigned short* __restrict__ wconv,
                                                   const float* __restrict__ cbias,
                                                   const float* __restrict__ residF,
                                                   float* __restrict__ outF,
                                                   unsigned short* __restrict__ outB,
                                                   int act) {
    __shared__ unsigned short sin_[240 * 72];  // 12 rows x 20 cols
    __shared__ unsigned short mid[192 * 72];   // 18x10 = 180 px (+12 pad)
    int tid = threadIdx.x;
    int bid = blockIdx.x;
    int b = bid >> 5;
    int rem = bid & 31;
    int ty = rem >> 2, tx = rem & 3;
    const unsigned short* inb = in + (size_t)b * 262144;

    int lane = tid & 63, w = tid >> 6;
    int l31 = lane & 31, kg8 = (lane >> 5) * 8, hi = lane >> 5;

    // da 1x1 B fragments into registers (tiny: 8 KB layer total)
    bh8 dB0[4], dB1[4];
#pragma unroll
    for (int cc = 0; cc < 4; ++cc) {
        dB0[cc] = *(const bh8*)&wda[((size_t)(cc * 2 + 0) * 64 + lane) * 8];
        dB1[cc] = *(const bh8*)&wda[((size_t)(cc * 2 + 1) * 64 + lane) * 8];
    }

    // stage input halo (20x12), zero-padded outside image
    for (int i = tid; i < 1920; i += 256) {
        int px = i >> 3, c8 = i & 7;
        int hy = px / 20, hx = px - hy * 20;
        int row = ty * 8 + hy - 2, col = tx * 16 + hx - 2;
        uint4 u = make_uint4(0u, 0u, 0u, 0u);
        if (row >= 0 && row < 64 && col >= 0 && col < 64)
            u = *(const uint4*)(inb + (((size_t)row * 64 + col) * 64 + c8 * 8));
        *(uint4*)&sin_[px * 72 + c8 * 8] = u;
    }
    __syncthreads();

    // depthwise 3x3 on 18x10 interior: thread = (c2 = channel pair, q = row)
    {
        int c2 = tid & 31, q = tid >> 5;  // q 0..7
        const float* kb = kerT + (size_t)b * 576 + 2 * c2;
        float ka[9], kbv[9];
#pragma unroll
        for (int t = 0; t < 9; ++t) {
            ka[t] = kb[t * 64];
            kbv[t] = kb[t * 64 + 1];
        }
#pragma unroll
        for (int rr = 0; rr < 2; ++rr) {
            int my = (rr == 0) ? q : 8 + q;
            if (rr == 1 && q >= 2) break;
            float m0[18], m1[18];
#pragma unroll
            for (int xx = 0; xx < 18; ++xx) { m0[xx] = 0.f; m1[xx] = 0.f; }
#pragma unroll
            for (int ky = 0; ky < 3; ++ky) {
                int sr = my + ky;
                float va[20], vb[20];
#pragma unroll
                for (int i = 0; i < 20; ++i) {
                    unsigned u = *(const unsigned*)&sin_[(sr * 20 + i) * 72 + 2 * c2];
                    va[i] = bf2f((unsigned short)(u & 0xffffu));
                    vb[i] = bf2f((unsigned short)(u >> 16));
                }
                float k0a = ka[ky * 3], k1a = ka[ky * 3 + 1], k2a = ka[ky * 3 + 2];
                float k0b = kbv[ky * 3], k1b = kbv[ky * 3 + 1], k2b = kbv[ky * 3 + 2];
#pragma unroll
                for (int xx = 0; xx < 18; ++xx) {
                    m0[xx] += k0a * va[xx] + k1a * va[xx + 1] + k2a * va[xx + 2];
                    m1[xx] += k0b * vb[xx] + k1b * vb[xx + 1] + k2b * vb[xx + 2];
                }
            }
#pragma unroll
            for (int xx = 0; xx < 18; ++xx) {
                unsigned u = (unsigned)f2bf(lrelu_f(m0[xx])) |
                             ((unsigned)f2bf(lrelu_f(m1[xx])) << 16);
                *(unsigned*)&mid[(my * 18 + xx) * 72 + 2 * c2] = u;
            }
        }
    }
    __syncthreads();

    // da 1x1 MFMA over 180 px (6 M-tiles); wave w does tiles {w, w+4}.
    // Writes da output (lrelu'd, CA residual added) back into mid in place.
    {
        float cb0 = cb[l31], cb1 = cb[32 + l31];
        float at0 = attv[b * 64 + l31], at1 = attv[b * 64 + 32 + l31];
        for (int mt = w; mt < 6; mt += 4) {
            f16acc a0 = {0,0,0,0,0,0,0,0,0,0,0,0,0,0,0,0};
            f16acc a1 = a0;
#pragma unroll
            for (int cc = 0; cc < 4; ++cc) {
                bh8 A = *(const bh8*)&mid[(mt * 32 + l31) * 72 + cc * 16 + kg8];
                MFMA32(a0, A, dB0[cc]);
                MFMA32(a1, A, dB1[cc]);
            }
#pragma unroll
            for (int r = 0; r < 16; ++r) {
                int rowm = (r & 3) + 8 * (r >> 2) + 4 * hi;
                int px = mt * 32 + rowm;
                if (px < 180) {
                    int my = px / 18, mx = px - my * 18;
                    int gy = ty * 8 + my - 1, gx = tx * 16 + mx - 1;
                    bool ok = (gy >= 0) && (gy < 64) && (gx >= 0) && (gx < 64);
                    int spx = (my + 1) * 20 + (mx + 1);
                    float i0v = bf2f(sin_[spx * 72 + l31]);
                    float i1v = bf2f(sin_[spx * 72 + 32 + l31]);
                    float v0 = lrelu_f(a0[r] + cb0 + i0v * at0);
                    float v1 = lrelu_f(a1[r] + cb1 + i1v * at1);
                    mid[px * 72 + l31] = ok ? f2bf(v0) : (unsigned short)0;
                    mid[px * 72 + 32 + l31] = ok ? f2bf(v1) : (unsigned short)0;
                }
            }
        }
    }

    // conv B prefetch queue
    const unsigned short* bp = wconv + (size_t)lane * 8;
    bh8 q0[6], q1[6];
#pragma unroll
    for (int i = 0; i < 6; ++i) {
        q0[i] = *(const bh8*)&bp[(size_t)i * 1024];
        q1[i] = *(const bh8*)&bp[(size_t)i * 1024 + 512];
    }
    __syncthreads();

    // 3x3 conv MFMA: wave w = M-tile w (px w*32..+31 of 16x8) x 2 N-tiles
    int p0 = w * 32 + l31;
    int ly0 = p0 >> 4, lx0 = p0 & 15;

    f16acc c0 = {0,0,0,0,0,0,0,0,0,0,0,0,0,0,0,0};
    f16acc c1 = c0;

#pragma unroll
    for (int c = 0; c < 36; ++c) {
        int t = c >> 2, cc = c & 3;
        int tyt = t / 3, txt = t - tyt * 3;
        int base = ((ly0 + tyt) * 18 + lx0 + txt) * 72 + cc * 16 + kg8;
        bh8 A = *(const bh8*)&mid[base];
        bh8 B0 = q0[c % 6], B1 = q1[c % 6];
        if (c + 6 < 36) {
            q0[c % 6] = *(const bh8*)&bp[(size_t)(c + 6) * 1024];
            q1[c % 6] = *(const bh8*)&bp[(size_t)(c + 6) * 1024 + 512];
        }
        MFMA32(c0, A, B0);
        MFMA32(c1, A, B1);
    }

    float bias0 = cbias[l31], bias1 = cbias[32 + l31];
    size_t outb = (size_t)b * 262144;
#pragma unroll
    for (int r = 0; r < 16; ++r) {
        int rowm = (r & 3) + 8 * (r >> 2) + 4 * hi;
        int m = w * 32 + rowm;
        int gy = ty * 8 + (m >> 4), gx = tx * 16 + (m & 15);
        size_t i0 = outb + (((size_t)gy * 64 + gx) * 64);
        float v0 = c0[r] + bias0, v1 = c1[r] + bias1;
        if (residF) {
            v0 += residF[i0 + l31];
            v1 += residF[i0 + 32 + l31];
        }
        if (act) { v0 = lrelu_f(v0); v1 = lrelu_f(v1); }
        if (outF) {
            outF[i0 + l31] = v0;
            outF[i0 + 32 + l31] = v1;
        }
        if (outB) {
            outB[i0 + l31] = f2bf(v0);
            outB[i0 + 32 + l31] = f2bf(v1);
        }
    }
}

// ---------------------------------------------------------------------------
// Up conv 64->256 (MFMA) + fused pixel shuffle. bf16 in/out.
// Tile 8x8 px, halo 10x10. Wave w: co [w*64, w*64+64). Grid 1024.
// ---------------------------------------------------------------------------
__global__ __launch_bounds__(256, 2) void up_mfma(const unsigned short* __restrict__ in,
                                                  const unsigned short* __restrict__ wp,
                                                  const float* __restrict__ bias,
                                                  unsigned short* __restrict__ shuf) {
    __shared__ unsigned short sm[100 * 72];
    int tid = threadIdx.x;
    int bid = blockIdx.x;
    int b = bid >> 6;
    int t6 = bid & 63;
    int ty = t6 >> 3, tx = t6 & 7;
    const unsigned short* inb = in + (size_t)b * 262144;

    int lane = tid & 63, w = tid >> 6;
    const unsigned short* bp = wp + (size_t)(w * 2) * 512 + (size_t)lane * 8;

    bh8 q0[4], q1[4];
#pragma unroll
    for (int i = 0; i < 4; ++i) {
        q0[i] = *(const bh8*)&bp[(size_t)i * 4096];
        q1[i] = *(const bh8*)&bp[(size_t)i * 4096 + 512];
    }

    for (int i = tid; i < 800; i += 256) {
        int px = i >> 3, c8 = i & 7;
        int hy = px / 10, hx = px - hy * 10;
        int row = ty * 8 + hy - 1, col = tx * 8 + hx - 1;
        uint4 u = make_uint4(0u, 0u, 0u, 0u);
        if (row >= 0 && row < 64 && col >= 0 && col < 64)
            u = *(const uint4*)(inb + (((size_t)row * 64 + col) * 64 + c8 * 8));
        *(uint4*)&sm[px * 72 + c8 * 8] = u;
    }
    __syncthreads();

    int l31 = lane & 31, kg8 = (lane >> 5) * 8;
    int ly0 = l31 >> 3, lx0 = l31 & 7;

    f16acc a00 = {0,0,0,0,0,0,0,0,0,0,0,0,0,0,0,0};
    f16acc a01 = a00, a10 = a00, a11 = a00;

#pragma unroll
    for (int c = 0; c < 36; ++c) {
        int t = c >> 2, cc = c & 3;
        int tyt = t / 3, txt = t - tyt * 3;
        int base0 = ((ly0 + tyt) * 10 + lx0 + txt) * 72 + cc * 16 + kg8;
        int base1 = base0 + 2880;
        bh8 A0 = *(const bh8*)&sm[base0];
        bh8 A1 = *(const bh8*)&sm[base1];
        bh8 B0 = q0[c % 4], B1 = q1[c % 4];
        if (c + 4 < 36) {
            q0[c % 4] = *(const bh8*)&bp[(size_t)(c + 4) * 4096];
            q1[c % 4] = *(const bh8*)&bp[(size_t)(c + 4) * 4096 + 512];
        }
        MFMA32(a00, A0, B0);
        MFMA32(a01, A0, B1);
        MFMA32(a10, A1, B0);
        MFMA32(a11, A1, B1);
    }

    int co0 = w * 64 + l31, co1 = co0 + 32;
    float bias0 = bias[co0], bias1 = bias[co1];
    int ch0 = co0 >> 2, r10 = (co0 >> 1) & 1, r20 = co0 & 1;
    int ch1 = co1 >> 2, r11 = (co1 >> 1) & 1, r21 = co1 & 1;
    int hi = lane >> 5;
#pragma unroll
    for (int r = 0; r < 16; ++r) {
        int rowm = (r & 3) + 8 * (r >> 2) + 4 * hi;
#pragma unroll
        for (int mt = 0; mt < 2; ++mt) {
            int m = mt * 32 + rowm;
            int y = ty * 8 + (m >> 3), x = tx * 8 + (m & 7);
            float va = (mt == 0) ? a00[r] : a10[r];
            float vb = (mt == 0) ? a01[r] : a11[r];
            shuf[(((size_t)b * 128 + 2 * y + r10) * 128 + 2 * x + r20) * 64 + ch0] = f2bf(va + bias0);
            shuf[(((size_t)b * 128 + 2 * y + r11) * 128 + 2 * x + r21) * 64 + ch1] = f2bf(vb + bias1);
        }
    }
}

// ---------------------------------------------------------------------------
// Tail conv 64->3 as MFMA, N padded to 32. shuf bf16 NHWC -> out NCHW fp32.
// ---------------------------------------------------------------------------
__global__ __launch_bounds__(256) void tail_mfma(const unsigned short* __restrict__ shuf,
                                                 const unsigned short* __restrict__ wp,
                                                 const float* __restrict__ bias,
                                                 float* __restrict__ outp) {
    __shared__ unsigned short sm[324 * 72];
    int tid = threadIdx.x;
    int bid = blockIdx.x;
    int b = bid >> 6;
    int rem = bid & 63;
    int ty = rem >> 3, tx = rem & 7;
    const unsigned short* sb = shuf + (size_t)b * 128 * 128 * 64;

    for (int i = tid; i < 2592; i += 256) {
        int px = i >> 3, c8 = i & 7;
        int hy = px / 18, hx = px - hy * 18;
        int row = ty * 16 + hy - 1, col = tx * 16 + hx - 1;
        uint4 u = make_uint4(0u, 0u, 0u, 0u);
        if (row >= 0 && row < 128 && col >= 0 && col < 128)
            u = *(const uint4*)(sb + (((size_t)row * 128 + col) * 64 + c8 * 8));
        *(uint4*)&sm[px * 72 + c8 * 8] = u;
    }
    __syncthreads();

    int lane = tid & 63, w = tid >> 6;
    int l31 = lane & 31, kg8 = (lane >> 5) * 8;
    int mbase = w * 64;
    int p0 = mbase + l31;
    int ly0 = p0 >> 4, lx0 = p0 & 15;

    f16acc a0 = {0,0,0,0,0,0,0,0,0,0,0,0,0,0,0,0};
    f16acc a1 = a0;

#pragma unroll
    for (int t = 0; t < 9; ++t) {
        int tyt = t / 3, txt = t - tyt * 3;
        int base0 = ((ly0 + tyt) * 18 + lx0 + txt) * 72 + kg8;
        int base1 = base0 + 2592;
#pragma unroll
        for (int cc = 0; cc < 4; ++cc) {
            int c = t * 4 + cc;
            bh8 A0 = *(const bh8*)&sm[base0 + cc * 16];
            bh8 A1 = *(const bh8*)&sm[base1 + cc * 16];
            bh8 B = *(const bh8*)&wp[((size_t)c * 64 + lane) * 8];
            MFMA32(a0, A0, B);
            MFMA32(a1, A1, B);
        }
    }

    if (l31 < 3) {
        float bv = bias[l31];
        int hi = lane >> 5;
        size_t ob = ((size_t)b * 3 + l31) * 16384;
#pragma unroll
        for (int r = 0; r < 16; ++r) {
            int rowm = (r & 3) + 8 * (r >> 2) + 4 * hi;
            int m0 = mbase + rowm;
            int gy0 = ty * 16 + (m0 >> 4), gx0 = tx * 16 + (m0 & 15);
            outp[ob + (size_t)gy0 * 128 + gx0] = a0[r] + bv;
            int m1 = m0 + 32;
            int gy1 = ty * 16 + (m1 >> 4), gx1 = tx * 16 + (m1 & 15);
            outp[ob + (size_t)gy1 * 128 + gx1] = a1[r] + bv;
        }
    }
}

// ---------------------------------------------------------------------------
extern "C" void kernel_launch(void* const* d_in, const int* in_sizes, int n_in,
                              void* d_out, int out_size, void* d_ws, size_t ws_size,
                              hipStream_t stream) {
    const float* x      = (const float*)d_in[0];
    const float* k_v    = (const float*)d_in[1];
    const float* head_w = (const float*)d_in[2];
    const float* head_b = (const float*)d_in[3];
    const float* comp_w = (const float*)d_in[4];
    const float* da_kw1 = (const float*)d_in[5];
    const float* da_kw2 = (const float*)d_in[6];
    const float* da_cw  = (const float*)d_in[7];
    const float* da_cb  = (const float*)d_in[8];
    const float* ca_w1  = (const float*)d_in[9];
    const float* ca_w2  = (const float*)d_in[10];
    const float* dab_cw = (const float*)d_in[11];
    const float* dab_cb = (const float*)d_in[12];
    const float* grp_w  = (const float*)d_in[13];
    const float* grp_b  = (const float*)d_in[14];
    const float* body_w = (const float*)d_in[15];
    const float* body_b = (const float*)d_in[16];
    const float* up_w   = (const float*)d_in[17];
    const float* up_b   = (const float*)d_in[18];
    const float* tail_w = (const float*)d_in[19];
    const float* tail_b = (const float*)d_in[20];

    char* base = (char*)d_ws;
    auto alloc = [&](size_t bytes) -> char* {
        char* p = base;
        base += (bytes + 255) & ~(size_t)255;
        return p;
    };
    unsigned short* wp_dab  = (unsigned short*)alloc((size_t)50 * 36864 * 2);
    unsigned short* wp_grp  = (unsigned short*)alloc((size_t)5 * 36864 * 2);
    unsigned short* wp_body = (unsigned short*)alloc((size_t)36864 * 2);
    unsigned short* wp_up   = (unsigned short*)alloc((size_t)147456 * 2);
    unsigned short* wp_da   = (unsigned short*)alloc((size_t)50 * 4096 * 2);
    unsigned short* wp_tail = (unsigned short*)alloc((size_t)18432 * 2);
    float* wT_head = (float*)alloc(1728 * 4);
    float* kvbuf   = (float*)alloc(1024 * 4);
    float* ker_all = (float*)alloc((size_t)460800 * 4);
    float* att_all = (float*)alloc((size_t)51200 * 4);
    const size_t ACT = (size_t)16 * 64 * 64 * 64;
    float* x0 = (float*)alloc(ACT * 4);
    float* rA = (float*)alloc(ACT * 4);
    float* rB = (float*)alloc(ACT * 4);
    float* rC = (float*)alloc(ACT * 4);
    unsigned short* sA = (unsigned short*)alloc(ACT * 2);
    unsigned short* sB = (unsigned short*)alloc(ACT * 2);
    unsigned short* sC = (unsigned short*)alloc(ACT * 2);
    unsigned short* t1 = (unsigned short*)alloc(ACT * 2);
    unsigned short* shuf = (unsigned short*)alloc((size_t)16 * 128 * 128 * 64 * 2);

    pack3x3<<<900, 256, 0, stream>>>(dab_cw, wp_dab, 50);
    pack3x3<<<90, 256, 0, stream>>>(grp_w, wp_grp, 5);
    pack3x3<<<18, 256, 0, stream>>>(body_w, wp_body, 1);
    pack_da<<<100, 256, 0, stream>>>(da_cw, wp_da, 50);
    pack_up<<<72, 256, 0, stream>>>(up_w, wp_up);
    pack_tail<<<9, 256, 0, stream>>>(tail_w, wp_tail);
    transpose_w<<<7, 256, 0, stream>>>(head_w, wT_head, 1, 64, 27);

    kv_kernel<<<16, 64, 0, stream>>>(k_v, comp_w, kvbuf);
    kerprep<<<800, 64, 0, stream>>>(kvbuf, da_kw1, da_kw2, ca_w1, ca_w2, ker_all, att_all);

    head_conv<<<2048, 256, 0, stream>>>(x, wT_head, head_b, x0, rA, sA);

    for (int g = 0; g < 5; ++g) {
        float* curF = rA;
        unsigned short* curS = sA;
        for (int n = 0; n < 5; ++n) {
            int l0 = (g * 5 + n) * 2, l1 = l0 + 1;
            // half 1: t1 = lrelu(conv1(lrelu(da0(cur))))
            dab_mfma<<<512, 256, 0, stream>>>(curS,
                                              wp_da + (size_t)l0 * 4096,
                                              da_cb + (size_t)l0 * 64,
                                              ker_all + (size_t)l0 * 9216,
                                              att_all + (size_t)l0 * 1024,
                                              wp_dab + (size_t)l0 * 36864,
                                              dab_cb + (size_t)l0 * 64,
                                              nullptr, nullptr, t1, 1);
            // half 2: res = conv2(lrelu(da1(t1))) + cur
            float* outF = (curF == rB) ? rC : rB;
            unsigned short* outS = (curS == sB) ? sC : sB;
            dab_mfma<<<512, 256, 0, stream>>>(t1,
                                              wp_da + (size_t)l1 * 4096,
                                              da_cb + (size_t)l1 * 64,
                                              ker_all + (size_t)l1 * 9216,
                                              att_all + (size_t)l1 * 1024,
                                              wp_dab + (size_t)l1 * 36864,
                                              dab_cb + (size_t)l1 * 64,
                                              curF, outF, outS, 0);
            curF = outF;
            curS = outS;
        }
        conv3x3_mfma<<<512, 256, 0, stream>>>(curS, wp_grp + (size_t)g * 36864,
                                              grp_b + (size_t)g * 64, rA, rC, sC, 0);
        float* tf = rA; rA = rC; rC = tf;
        unsigned short* ts = sA; sA = sC; sC = ts;
    }
    conv3x3_mfma<<<512, 256, 0, stream>>>(sA, wp_body, body_b, x0, nullptr, t1, 0);

    up_mfma<<<1024, 256, 0, stream>>>(t1, wp_up, up_b, shuf);
    tail_mfma<<<1024, 256, 0, stream>>>(shuf, wp_tail, tail_b, (float*)d_out);
}